// Round 7
// baseline (903.576 us; speedup 1.0000x reference)
//
#include <hip/hip_runtime.h>
#include <math.h>

// DASCO forward, round 16: B operand read L2-direct, LDS carries A only.
// R15 counters fit a clean model: per 128x128x32 block-step the LDS port moves
// 48KB (A+B reads + glds writes) at 128B/cyc -> ~1125 cyc/CU vs ~234 cyc MFMA
// demand = 21% MfmaUtil ceiling (measured 20.8). Every B operand here is
// L2-resident per z (<= 2.25MB), and the 16x16x32 B-fragment layout is exactly
// a coalesced 16-line global read -> bfr[] loads straight from L2, Bs[] LDS
// buffer deleted. LDS traffic halves (24KB/step), L2 takes the B stream
// (~50% L1-filtered via 128B-line reuse across K-steps). A path, sync, and
// epilogue identical to R15's proven R0 geometry. B=32, S=512, D=768, M=384.

typedef __bf16 bf16x8 __attribute__((ext_vector_type(8)));
typedef __bf16 bf16x4 __attribute__((ext_vector_type(4)));
typedef float f32x4 __attribute__((ext_vector_type(4)));

__device__ __forceinline__ void glds16(const void* g, void* l) {
    __builtin_amdgcn_global_load_lds(
        (const __attribute__((address_space(1))) unsigned*)g,
        (__attribute__((address_space(3))) unsigned*)l, 16, 0, 0);
}

__device__ __forceinline__ float sigf(float x) { return 1.f / (1.f + __expf(-x)); }

// ---------------- bf16 MFMA GEMM, 128x128 tile, A-LDS dbuf + B-L2-direct ------
// C[z][m][n] = sum_k A[z][m][k]*B[z][n][k] (+bias[(z/bzDiv)*bzStride + n]),
// act: 0 none; 1 relu; 2 elu; 4 relu+gate (E bf16, H_prev). n < nMax masked.
__global__ __launch_bounds__(256) void mfma_gemm(
    const __bf16* __restrict__ A, const __bf16* __restrict__ B,
    const float* __restrict__ bias, int bzDiv, int bzStride,
    const __bf16* __restrict__ E,
    float* __restrict__ Cf, __bf16* __restrict__ Cb,
    int K, int lda, int ldb, int ldc, int nMax,
    long sAo, long sAi, long sBo, long sBi, int zInner, long sC, int act)
{
    __shared__ __bf16 As[2][128 * 32];   // 8KB x2 (A only; B never staged)
    int z = blockIdx.z;
    long aBase = (long)(z / zInner) * sAo + (long)(z % zInner) * sAi;
    long bBase = (long)(z / zInner) * sBo + (long)(z % zInner) * sBi;
    long cBase = (long)z * sC;
    int m0 = blockIdx.x * 128, n0 = blockIdx.y * 128;
    int tid = threadIdx.x;
    int wave = tid >> 6, lane = tid & 63;
    int wm = wave >> 1, wn = wave & 1;
    int rl = lane & 15, quad = lane >> 4;

    int e0 = tid, e1 = tid + 256;
    const __bf16* Ag0 = A + aBase + (long)(m0 + (e0 >> 2)) * lda + (e0 & 3) * 8;
    const __bf16* Ag1 = A + aBase + (long)(m0 + (e1 >> 2)) * lda + (e1 & 3) * 8;

    // B fragment base pointers: lane (rl,quad) of wave wn reads rows
    // n0 + wn*64 + ni*16 + rl, k-chunk quad*8 — 64 lanes = 16 full 64B lines.
    int brow = wn * 64 + rl;
    const __bf16* Bf[4];
#pragma unroll
    for (int ni = 0; ni < 4; ni++)
        Bf[ni] = B + bBase + (long)(n0 + brow + ni * 16) * ldb + quad * 8;

    f32x4 acc[4][4];
#pragma unroll
    for (int i = 0; i < 4; i++)
#pragma unroll
        for (int j = 0; j < 4; j++) acc[i][j] = (f32x4){0.f, 0.f, 0.f, 0.f};

    int arow = wm * 64 + rl;

    glds16(Ag0, As[0] + e0 * 8); glds16(Ag1, As[0] + e1 * 8);

    int cur = 0;
    for (int k0 = 0; k0 < K; k0 += 32) {
        __syncthreads();
        // B loads first (plain global, retire before the glds16 below in FIFO
        // order -> compiler can use a counted vmcnt and leave A in flight).
        bf16x8 bfr[4];
#pragma unroll
        for (int ni = 0; ni < 4; ni++)
            bfr[ni] = *(const bf16x8*)(Bf[ni] + k0);
        if (k0 + 32 < K) {
            int nk = k0 + 32, nb = cur ^ 1;
            glds16(Ag0 + nk, As[nb] + e0 * 8); glds16(Ag1 + nk, As[nb] + e1 * 8);
        }
        const bf16x8* Asv = (const bf16x8*)As[cur];
        bf16x8 af[4];
#pragma unroll
        for (int mi = 0; mi < 4; mi++) af[mi] = Asv[(arow + mi * 16) * 4 + quad];
#pragma unroll
        for (int mi = 0; mi < 4; mi++)
#pragma unroll
            for (int ni = 0; ni < 4; ni++)
                acc[mi][ni] = __builtin_amdgcn_mfma_f32_16x16x32_bf16(
                    af[mi], bfr[ni], acc[mi][ni], 0, 0, 0);
        cur ^= 1;
    }

    int crow = m0 + wm * 64 + quad * 4;
    int ccol = n0 + wn * 64 + rl;
    const float* biasz = bias ? bias + (z / bzDiv) * bzStride : nullptr;
    float bv[4];
#pragma unroll
    for (int ni = 0; ni < 4; ni++) {
        int col = ccol + ni * 16;
        bv[ni] = (biasz && col < nMax) ? biasz[col] : 0.f;
    }
#pragma unroll
    for (int mi = 0; mi < 4; mi++) {
#pragma unroll
        for (int ni = 0; ni < 4; ni++) {
            int col = ccol + ni * 16;
            if (col >= nMax) continue;
#pragma unroll
            for (int r = 0; r < 4; r++) {
                float v = acc[mi][ni][r] + bv[ni];
                long idx = cBase + (long)(crow + mi * 16 + r) * ldc + col;
                if (act == 1) v = fmaxf(v, 0.f);
                else if (act == 2) v = (v > 0.f) ? v : expm1f(v);
                else if (act == 4) {
                    float e = (float)E[idx];
                    v = fmaxf(v, 0.f);
                    float g = sigf(e);
                    v = g * v + (1.f - g) * e;
                }
                if (Cf) Cf[idx] = v;
                if (Cb) Cb[idx] = (__bf16)v;
            }
        }
    }
}

// ---------------- fused weight transpose-casts (10 weights, one dispatch) -----
struct WCast {
    const float* src[10];
    unsigned dstOff[10];
    int R[10], C[10];
    int start[11];
};

__global__ __launch_bounds__(256) void castW_kernel(WCast wc, __bf16* wb)
{
    __shared__ float t[32][33];
    int bid = blockIdx.x;
    int e = 0;
    while (bid >= wc.start[e + 1]) e++;
    int tt = bid - wc.start[e];
    int cT = wc.C[e] >> 5;
    int ty = tt / cT, tx = tt - ty * cT;
    const float* in = wc.src[e];
    __bf16* out = wb + wc.dstOff[e];
    int R = wc.R[e], C = wc.C[e];
    int r0 = ty * 32, c0 = tx * 32;
    int tid = threadIdx.x;
    int r = tid >> 3, c4 = (tid & 7) * 4;
    float4 v = *(const float4*)(in + (long)(r0 + r) * C + c0 + c4);
    t[r][c4] = v.x; t[r][c4 + 1] = v.y; t[r][c4 + 2] = v.z; t[r][c4 + 3] = v.w;
    __syncthreads();
    int c = tid >> 3, r4 = (tid & 7) * 4;
    bf16x4 o;
    o[0] = (__bf16)t[r4 + 0][c]; o[1] = (__bf16)t[r4 + 1][c];
    o[2] = (__bf16)t[r4 + 2][c]; o[3] = (__bf16)t[r4 + 3][c];
    *(bf16x4*)(out + (long)(c0 + c) * R + r0 + r4) = o;
}

// ---------------- plain casts ----------------
__global__ void cast_bf16_kernel(const float* __restrict__ in, __bf16* __restrict__ out, long n4)
{
    long i = (long)blockIdx.x * blockDim.x + threadIdx.x;
    if (i < n4) {
        float4 v = ((const float4*)in)[i];
        bf16x4 o; o[0] = (__bf16)v.x; o[1] = (__bf16)v.y; o[2] = (__bf16)v.z; o[3] = (__bf16)v.w;
        ((bf16x4*)out)[i] = o;
    }
}

// ---------------- attention softmax + head-mean -> adj_ag (bf16 in/out) -------
__global__ __launch_bounds__(256) void softmax_combine(
    const __bf16* __restrict__ scores, const int* __restrict__ attn_mask,
    __bf16* __restrict__ adj_agb, int b0)
{
    const int S = 512;
    int s = blockIdx.x, bl = blockIdx.y, b = b0 + bl;
    int tid = threadIdx.x;
    const float scale = 0.1020620726159658f;  // 1/sqrt(96)
    int t0 = tid, t1 = tid + 256;
    int cm0 = attn_mask[b * S + t0], cm1 = attn_mask[b * S + t1];
    float vals[8][2], part[8];
#pragma unroll
    for (int h = 0; h < 8; ++h) {
        long rb = ((long)(bl * 8 + h) * S + s) * S;
        float r0 = (float)scores[rb + t0], r1 = (float)scores[rb + t1];
        vals[h][0] = cm0 ? __expf(r0 * scale) : 0.f;
        vals[h][1] = cm1 ? __expf(r1 * scale) : 0.f;
        part[h] = vals[h][0] + vals[h][1];
    }
    __shared__ float red[4][8];
    __shared__ float linv[8];
    int lane = tid & 63, w = tid >> 6;
#pragma unroll
    for (int h = 0; h < 8; ++h) {
        float v = part[h];
        for (int o = 32; o > 0; o >>= 1) v += __shfl_down(v, o);
        if (lane == 0) red[w][h] = v;
    }
    __syncthreads();
    if (tid < 8) {
        float l = red[0][tid] + red[1][tid] + red[2][tid] + red[3][tid];
        linv[tid] = 1.f / fmaxf(l, 1e-30f);
    }
    __syncthreads();
    float rowmask = attn_mask[b * S + s] ? 1.f : 0.f;
    float a0 = 0.f, a1 = 0.f;
#pragma unroll
    for (int h = 0; h < 8; ++h) { a0 += vals[h][0] * linv[h]; a1 += vals[h][1] * linv[h]; }
    a0 *= 0.125f; a1 *= 0.125f;
    if (t0 == s) a0 = 1.f;
    if (t1 == s) a1 = 1.f;
    long ob = ((long)b * S + s) * S;
    adj_agb[ob + t0] = (__bf16)(rowmask * a0);
    adj_agb[ob + t1] = (__bf16)(rowmask * a1);
}

// ---------------- gcn combine (bf16 in/out) ----------------
// IsIdb: [2][MT][384] bf16 (sem then dep). Icom = (1-0.6 sig(d)) s + 0.6 sig(d) d
__global__ void gcn_combine2(const __bf16* __restrict__ IsIdb,
                             __bf16* __restrict__ Icomb, long n8)
{
    long i = (long)blockIdx.x * blockDim.x + threadIdx.x;
    if (i >= n8) return;
    bf16x8 sv = ((const bf16x8*)IsIdb)[i];
    bf16x8 dv = ((const bf16x8*)(IsIdb + n8 * 8))[i];
    bf16x8 o;
#pragma unroll
    for (int j = 0; j < 8; j++) {
        float s = (float)sv[j], d = (float)dv[j];
        float g = 0.6f * sigf(d);
        o[j] = (__bf16)((1.f - g) * s + g * d);
    }
    ((bf16x8*)Icomb)[i] = o;
}

// ---------------- row L2-normalize, bf16 in place ----------------
__global__ __launch_bounds__(128) void rownorm(__bf16* __restrict__ hb, int Dm)
{
    __bf16* p = hb + (long)blockIdx.x * Dm;
    int tid = threadIdx.x;
    float ss = 0.f;
    for (int i = tid; i < Dm; i += 128) { float v = (float)p[i]; ss += v * v; }
    for (int o = 32; o > 0; o >>= 1) ss += __shfl_down(ss, o);
    __shared__ float sb[2];
    __shared__ float scale;
    if ((tid & 63) == 0) sb[tid >> 6] = ss;
    __syncthreads();
    if (tid == 0) scale = 1.f / fmaxf(sqrtf(sb[0] + sb[1]), 1e-12f);
    __syncthreads();
    for (int i = tid; i < Dm; i += 128) p[i] = (__bf16)((float)p[i] * scale);
}

// ---------------- fused symmetric scope loss per (b,s) row (bf16 G) -----------
// G21 is never materialized: G21[b,s,t] == G12[b,t,s] (bitwise-identical MFMA
// sums), read as a strided column gather; adjacent s-blocks share L2 lines.
__global__ __launch_bounds__(256) void loss_kernel(
    const __bf16* __restrict__ G11, const __bf16* __restrict__ G12,
    const __bf16* __restrict__ G22,
    const int* __restrict__ s_mask, const int* __restrict__ a_mask,
    float* __restrict__ lossb)
{
    const int S = 512;
    int s = blockIdx.x, b = blockIdx.y;
    int tid = threadIdx.x;
    if (a_mask[b * S + s] == 0) {
        if (tid == 0) lossb[b * S + s] = 0.f;
        return;
    }
    long base = ((long)b * S + s) * S;
    long cbase = (long)b * S * S + s;  // G12 column s (== G21 row s)
    const float it = 1.f / 0.07f;
    float sms = s_mask[b * S + s] ? 1.f : 0.f;
    float d12 = (float)G12[base + s];          // == G21 diag (same dot product)
    float w1i = sms * d12 * it, w2i = w1i;
    float p[8];
#pragma unroll
    for (int h = 0; h < 8; h++) p[h] = 0.f;
#pragma unroll
    for (int j = 0; j < 2; j++) {
        int t = tid + j * 256;
        bool smt = s_mask[b * S + t] != 0;
        bool off = (t != s);
        float g11 = (float)G11[base + t], g12 = (float)G12[base + t];
        float g21 = (float)G12[cbase + (long)t * S];
        float g22 = (float)G22[base + t];
        float e11 = __expf(g11 * it), e12 = __expf(g12 * it);
        float e21 = __expf(g21 * it), e22 = __expf(g22 * it);
        p[2] += e11; p[3] += e12; p[6] += e22; p[7] += e21;
        if (off) {
            p[0] += smt ? e11 : 1.f;
            p[4] += smt ? e22 : 1.f;
            p[1] += smt ? __expf(g12 * w1i) : 1.f;
            p[5] += smt ? __expf(g21 * w2i) : 1.f;
        }
    }
    __shared__ float red[4][8];
    int lane = tid & 63, w = tid >> 6;
#pragma unroll
    for (int h = 0; h < 8; h++) {
        float v = p[h];
        for (int o = 32; o > 0; o >>= 1) v += __shfl_down(v, o);
        if (lane == 0) red[w][h] = v;
    }
    __syncthreads();
    if (tid == 0) {
        float r[8];
#pragma unroll
        for (int h = 0; h < 8; h++) r[h] = red[0][h] + red[1][h] + red[2][h] + red[3][h];
        float g11ss = (float)G11[base + s], g22ss = (float)G22[base + s];
        float pos1 = __expf(w1i) + r[0] + r[1];
        float alle1 = r[2] - __expf(g11ss * it) + r[3];
        float pos2 = __expf(w2i) + r[4] + r[5];
        float alle2 = r[6] - __expf(g22ss * it) + r[7];
        lossb[b * S + s] = 0.5f * ((__logf(alle1) - __logf(pos1)) +
                                   (__logf(alle2) - __logf(pos2)));
    }
}

__global__ __launch_bounds__(256) void final_reduce(
    const float* __restrict__ lossb, float* __restrict__ out, int n)
{
    int tid = threadIdx.x;
    float s = 0.f;
    for (int i = tid; i < n; i += 256) s += lossb[i];
    for (int o = 32; o > 0; o >>= 1) s += __shfl_down(s, o);
    __shared__ float sb[4];
    if ((tid & 63) == 0) sb[tid >> 6] = s;
    __syncthreads();
    if (tid == 0) out[0] = (sb[0] + sb[1] + sb[2] + sb[3]) / (float)n;
}

// ---------------- host ----------------
static inline void mg(hipStream_t st, const __bf16* A, const __bf16* B,
                      const float* bias, int bzDiv, int bzStride,
                      const __bf16* E, float* Cf, __bf16* Cb,
                      int M, int Npad, int nMax, int K, int lda, int ldb, int ldc,
                      long sAo, long sAi, long sBo, long sBi, int zInner, long sC, int nz,
                      int act)
{
    dim3 g(M / 128, Npad / 128, nz);
    mfma_gemm<<<g, 256, 0, st>>>(A, B, bias, bzDiv, bzStride, E, Cf, Cb,
                                 K, lda, ldb, ldc, nMax,
                                 sAo, sAi, sBo, sBi, zInner, sC, act);
}

extern "C" void kernel_launch(void* const* d_in, const int* in_sizes, int n_in,
                              void* d_out, int out_size, void* d_ws, size_t ws_size,
                              hipStream_t stream)
{
    const int B = 32, S = 512, D = 768, Mm = 384;
    const int MT = B * S;  // 16384
    const float* X    = (const float*)d_in[0];
    const float* adjm = (const float*)d_in[1];
    const int* attn_mask = (const int*)d_in[2];
    const int* s_mask    = (const int*)d_in[3];
    const int* a_mask    = (const int*)d_in[4];
    const float* Wq = (const float*)d_in[5],  *bq = (const float*)d_in[6];
    const float* Wk = (const float*)d_in[7],  *bk = (const float*)d_in[8];
    const float* semW0 = (const float*)d_in[9],  *semb0 = (const float*)d_in[10];
    const float* semW1 = (const float*)d_in[11], *semb1 = (const float*)d_in[12];
    const float* depW0 = (const float*)d_in[13], *depb0 = (const float*)d_in[14];
    const float* depW1 = (const float*)d_in[15], *depb1 = (const float*)d_in[16];
    const float* fc1W = (const float*)d_in[17], *fc1b = (const float*)d_in[18];
    const float* fc2W = (const float*)d_in[19], *fc2b = (const float*)d_in[20];
    const float* fc3W = (const float*)d_in[21], *fc3b = (const float*)d_in[22];
    const float* fc4W = (const float*)d_in[23], *fc4b = (const float*)d_in[24];

    char* ws = (char*)d_ws;
    const size_t MB = 1u << 20;
    const size_t KB = 1u << 10;

    // rotating regions
    __bf16* Xb      = (__bf16*)(ws + 0 * MB);     // 24MB
    __bf16* adj_agb = (__bf16*)(ws + 24 * MB);    // 16MB \ contiguous
    __bf16* adjmb   = (__bf16*)(ws + 40 * MB);    // 16MB /
    __bf16* qkb     = (__bf16*)(ws + 56 * MB);    // 48MB (attn)
    __bf16* scoreB  = (__bf16*)(ws + 104 * MB);   // 64MB chunk (attn), ends 168
    __bf16* P64     = (__bf16*)(ws + 56 * MB);    // 24MB [64][384][512] (layers)
    __bf16* IsIdb   = (__bf16*)(ws + 80 * MB);    // 24MB [2][MT][384] bf16
    __bf16* Isemb   = IsIdb;                      // sem half doubles as proj input
    __bf16* Icomb   = (__bf16*)(ws + 104 * MB);   // 12MB (scoreB dead)
    __bf16* Hpreb   = (__bf16*)(ws + 116 * MB);   // 12MB (fc4 out, pre-gate)
    __bf16* Hb      = (__bf16*)(ws + 128 * MB);   // 12MB (gated H)
    __bf16* t1b     = (__bf16*)(ws + 0 * MB);     // 2MB, 2 slices (Xb dead)
    __bf16* hb12    = (__bf16*)(ws + 140 * MB);   // 24MB [2][MT][384] h1|h2
    __bf16* h1b     = hb12;
    __bf16* h2b     = hb12 + (long)MT * Mm;
    __bf16* G11     = (__bf16*)(ws + 24 * MB);    // 16MB (adj dead)
    __bf16* G12     = (__bf16*)(ws + 40 * MB);    // 16MB
    __bf16* G22     = (__bf16*)(ws + 72 * MB);    // 16MB (G21 slot unused)

    // permanent weight region @192MB
    char* wreg = ws + 192 * MB;
    __bf16* wb     = (__bf16*)wreg;
    __bf16* WqkT   = (__bf16*)(wreg + 0 * KB);       // [1536][768]
    __bf16* semW0T = (__bf16*)(wreg + 2304 * KB);    // [384][768] \ contiguous
    __bf16* depW0T = (__bf16*)(wreg + 2880 * KB);    //            /
    __bf16* fc4WT  = (__bf16*)(wreg + 3456 * KB);
    __bf16* semW1T = (__bf16*)(wreg + 4032 * KB);    // [384][384] \ contiguous
    __bf16* depW1T = (__bf16*)(wreg + 4320 * KB);    //            /
    __bf16* fc3WT  = (__bf16*)(wreg + 4608 * KB);
    __bf16* fc1WT  = (__bf16*)(wreg + 4896 * KB);    // [128 pad][384]
    __bf16* fc2WT  = (__bf16*)(wreg + 4992 * KB);    // [384][32]
    float*  bqk    = (float*)(wreg + 5016 * KB);     // [1536]
    float*  sbd0   = (float*)(wreg + 5024 * KB);     // [768] semb0|depb0
    float*  sbd1   = (float*)(wreg + 5028 * KB);     // [768] semb1|depb1
    float*  lossb  = (float*)(wreg + 5036 * KB);     // 64KB

    long nSM = (long)S * Mm, nSS = (long)S * S;
    long nPM = (long)Mm * S;

    // ---- casts ----
    cast_bf16_kernel<<<(MT * D / 4 + 255) / 256, 256, 0, stream>>>(X, Xb, (long)MT * D / 4);
    cast_bf16_kernel<<<((long)B * nSS / 4 + 255) / 256, 256, 0, stream>>>(adjm, adjmb, (long)B * nSS / 4);
    {
        WCast wc;
        const float* srcs[10] = {Wq, Wk, semW0, depW0, fc4W, semW1, depW1, fc3W, fc1W, fc2W};
        unsigned offs[10] = {0u, 589824u, 1179648u, 1474560u, 1769472u,
                             2064384u, 2211840u, 2359296u, 2506752u, 2555904u};
        int Rs[10] = {768, 768, 768, 768, 768, 384, 384, 384, 384, 32};
        int Cs[10] = {768, 768, 384, 384, 384, 384, 384, 384, 32, 384};
        int st = 0;
        for (int i = 0; i < 10; i++) {
            wc.src[i] = srcs[i]; wc.dstOff[i] = offs[i];
            wc.R[i] = Rs[i]; wc.C[i] = Cs[i];
            wc.start[i] = st; st += (Rs[i] / 32) * (Cs[i] / 32);
        }
        wc.start[10] = st;  // 2472
        castW_kernel<<<st, 256, 0, stream>>>(wc, wb);
    }
    hipMemsetAsync(fc1WT + 32 * Mm, 0, (size_t)96 * Mm * 2, stream);
    hipMemcpyAsync(bqk, bq, D * 4, hipMemcpyDeviceToDevice, stream);
    hipMemcpyAsync(bqk + D, bk, D * 4, hipMemcpyDeviceToDevice, stream);
    hipMemcpyAsync(sbd0, semb0, Mm * 4, hipMemcpyDeviceToDevice, stream);
    hipMemcpyAsync(sbd0 + Mm, depb0, Mm * 4, hipMemcpyDeviceToDevice, stream);
    hipMemcpyAsync(sbd1, semb1, Mm * 4, hipMemcpyDeviceToDevice, stream);
    hipMemcpyAsync(sbd1 + Mm, depb1, Mm * 4, hipMemcpyDeviceToDevice, stream);

    // ---- fused q|k projection ----
    mg(stream, Xb, WqkT, bqk, 1, 0, nullptr, nullptr, qkb, MT, 1536, 1536, D,
       D, D, 1536, 0, 0, 0, 0, 1, 0, 1, 0);

    // ---- attention: materialized bf16 scores, 2 chunks of 16 batches ----
    for (int c = 0; c < 2; c++) {
        const __bf16* qc = qkb + (long)c * 16 * S * 1536;
        mg(stream, qc, qc + 768, nullptr, 1, 0, nullptr, nullptr, scoreB, S, S, S, 96,
           1536, 1536, S, (long)S * 1536, 96, (long)S * 1536, 96, 8, nSS, 128, 0);
        softmax_combine<<<dim3(S, 16), 256, 0, stream>>>(scoreB, attn_mask, adj_agb, c * 16);
    }

    long n8 = (long)MT * Mm / 8;
    int cwg = (int)((n8 + 255) / 256);

    // ---- layer 0 ----
    // P64[z<32] = (X_b @ semW0)^T, P64[z>=32] = (X_b @ depW0)^T
    mg(stream, semW0T, Xb, nullptr, 1, 0, nullptr, nullptr, P64, Mm, S, S, D,
       D, D, S, (long)Mm * D, 0, 0, (long)S * D, 32, nPM, 64, 0);
    // merged adjacency: z<32 adj_ag@Psem+semb0 -> Isem; z>=32 adjm@Pdep+depb0 -> Idep (bf16)
    mg(stream, adj_agb, P64, sbd0, 32, Mm, nullptr, nullptr, IsIdb, S, Mm, Mm, S,
       S, S, Mm, 0, nSS, 0, nPM, 64, nSM, 64, 0);
    gcn_combine2<<<cwg, 256, 0, stream>>>(IsIdb, Icomb, n8);
    // Hpre = X @ fc4W + fc4b  (bf16)
    mg(stream, Xb, fc4WT, fc4b, 1, 0, nullptr, nullptr, Hpreb, MT, Mm, Mm, D,
       D, D, Mm, 0, 0, 0, 0, 1, 0, 1, 0);
    // Hb = gate(Hpre, relu(Icom @ fc3W + fc3b))
    mg(stream, Icomb, fc3WT, fc3b, 1, 0, Hpreb, nullptr, Hb, MT, Mm, Mm, Mm,
       Mm, Mm, Mm, 0, 0, 0, 0, 1, 0, 1, 4);

    // ---- layer 1 ----
    mg(stream, semW1T, Hb, nullptr, 1, 0, nullptr, nullptr, P64, Mm, S, S, Mm,
       Mm, Mm, S, (long)Mm * Mm, 0, 0, nSM, 32, nPM, 64, 0);
    mg(stream, adj_agb, P64, sbd1, 32, Mm, nullptr, nullptr, IsIdb, S, Mm, Mm, S,
       S, S, Mm, 0, nSS, 0, nPM, 64, nSM, 64, 0);
    gcn_combine2<<<cwg, 256, 0, stream>>>(IsIdb, Icomb, n8);
    // Hb = gate(Hb, relu(Icom @ fc3W + fc3b))  (in place; per-thread read-then-write)
    mg(stream, Icomb, fc3WT, fc3b, 1, 0, Hb, nullptr, Hb, MT, Mm, Mm, Mm,
       Mm, Mm, Mm, 0, 0, 0, 0, 1, 0, 1, 4);

    // ---- projection heads, z=2 (z0: Hb->h1, z1: Isemb->h2) ----
    long sAproj = (long)(Isemb - Hb);  // constant offset between the two A bases
    mg(stream, Hb, fc1WT, fc1b, 1, 0, nullptr, nullptr, t1b, MT, 128, 32, Mm,
       Mm, Mm, 32, 0, sAproj, 0, 0, 2, (long)MT * 32, 2, 2);
    mg(stream, t1b, fc2WT, fc2b, 1, 0, nullptr, nullptr, hb12, MT, Mm, Mm, 32,
       32, 32, Mm, 0, (long)MT * 32, 0, 0, 2, (long)MT * Mm, 2, 0);

    rownorm<<<2 * MT, 128, 0, stream>>>(hb12, Mm);

    // ---- Gram matrices (bf16): G11|G12 (z=64), G22 only (z=32; G21 == G12^T) ----
    mg(stream, h1b, h1b, nullptr, 1, 0, nullptr, nullptr, G11, S, S, S, Mm,
       Mm, Mm, S, 0, nSM, 32 * nSM, nSM, 32, nSS, 64, 0);   // G11 | G12
    mg(stream, h2b, h2b, nullptr, 1, 0, nullptr, nullptr, G22, S, S, S, Mm,
       Mm, Mm, S, 0, nSM, 0, nSM, 32, nSS, 32, 0);          // G22

    // ---- loss ----
    loss_kernel<<<dim3(S, B), 256, 0, stream>>>(G11, G12, G22, s_mask, a_mask, lossb);
    final_reduce<<<1, 256, 0, stream>>>(lossb, (float*)d_out, MT);
}

// Round 8
// 848.729 us; speedup vs baseline: 1.0646x; 1.0646x over previous
//
#include <hip/hip_runtime.h>
#include <math.h>

// DASCO forward, round 17: dispatch-graph fusion on top of the proven R15 GEMM
// core (untouched: 128x128 tile, 4 waves 2x2, acc 4x4, __syncthreads dbuf —
// the m97-structure ceiling of ~21% MfmaUtil is established after 7 rounds:
// pipelining null, swizzle null, bigger tile = occupancy cliff, B-from-L2
// negative since per-CU L2 BW < LDS port). This round: (1) fc4 fused into the
// q|k dispatch (shared A=Xb; weights reordered so WqkT|fc4WT contiguous ->
// one N=1920 dispatch replaces q|k + a 384-block underoccupied fc4); (2)
// gcn_combine fused into the dep-adjacency epilogue (act=5, E=Isem via new
// ldE/sCE params) killing 2 dispatches + the IsIdb dep-half round-trip.
// B=32, S=512, D=768, M=384.

typedef __bf16 bf16x8 __attribute__((ext_vector_type(8)));
typedef __bf16 bf16x4 __attribute__((ext_vector_type(4)));
typedef float f32x4 __attribute__((ext_vector_type(4)));

__device__ __forceinline__ void glds16(const void* g, void* l) {
    __builtin_amdgcn_global_load_lds(
        (const __attribute__((address_space(1))) unsigned*)g,
        (__attribute__((address_space(3))) unsigned*)l, 16, 0, 0);
}

__device__ __forceinline__ float sigf(float x) { return 1.f / (1.f + __expf(-x)); }

// ---------------- bf16 MFMA GEMM, 128x128 tile, dbuf (R15 core) ---------------
// C[z][m][n] = sum_k A[z][m][k]*B[z][n][k] (+bias[(z/bzDiv)*bzStride + n]).
// act: 0 none; 1 relu; 2 elu; 4 gate: g=sig(E), out=g*relu(v)+(1-g)*E;
// 5 gcn-combine: g=0.6*sig(v), out=(1-g)*E+g*v.  E addressed as
// E[z*sCE + row*ldE + col]. n < nMax masked.
__global__ __launch_bounds__(256) void mfma_gemm(
    const __bf16* __restrict__ A, const __bf16* __restrict__ B,
    const float* __restrict__ bias, int bzDiv, int bzStride,
    const __bf16* __restrict__ E, long ldE, long sCE,
    float* __restrict__ Cf, __bf16* __restrict__ Cb,
    int K, int lda, int ldb, int ldc, int nMax,
    long sAo, long sAi, long sBo, long sBi, int zInner, long sC, int act)
{
    __shared__ __bf16 As[2][128 * 32];
    __shared__ __bf16 Bs[2][128 * 32];
    int z = blockIdx.z;
    long aBase = (long)(z / zInner) * sAo + (long)(z % zInner) * sAi;
    long bBase = (long)(z / zInner) * sBo + (long)(z % zInner) * sBi;
    long cBase = (long)z * sC;
    int m0 = blockIdx.x * 128, n0 = blockIdx.y * 128;
    int tid = threadIdx.x;
    int wave = tid >> 6, lane = tid & 63;
    int wm = wave >> 1, wn = wave & 1;

    int e0 = tid, e1 = tid + 256;
    const __bf16* Ag0 = A + aBase + (long)(m0 + (e0 >> 2)) * lda + (e0 & 3) * 8;
    const __bf16* Ag1 = A + aBase + (long)(m0 + (e1 >> 2)) * lda + (e1 & 3) * 8;
    const __bf16* Bg0 = B + bBase + (long)(n0 + (e0 >> 2)) * ldb + (e0 & 3) * 8;
    const __bf16* Bg1 = B + bBase + (long)(n0 + (e1 >> 2)) * ldb + (e1 & 3) * 8;

    f32x4 acc[4][4];
#pragma unroll
    for (int i = 0; i < 4; i++)
#pragma unroll
        for (int j = 0; j < 4; j++) acc[i][j] = (f32x4){0.f, 0.f, 0.f, 0.f};

    int arow = wm * 64 + (lane & 15);
    int brow = wn * 64 + (lane & 15);
    int quad = lane >> 4;

    glds16(Ag0, As[0] + e0 * 8); glds16(Ag1, As[0] + e1 * 8);
    glds16(Bg0, Bs[0] + e0 * 8); glds16(Bg1, Bs[0] + e1 * 8);

    int cur = 0;
    for (int k0 = 0; k0 < K; k0 += 32) {
        __syncthreads();
        if (k0 + 32 < K) {
            int nk = k0 + 32, nb = cur ^ 1;
            glds16(Ag0 + nk, As[nb] + e0 * 8); glds16(Ag1 + nk, As[nb] + e1 * 8);
            glds16(Bg0 + nk, Bs[nb] + e0 * 8); glds16(Bg1 + nk, Bs[nb] + e1 * 8);
        }
        const bf16x8* Asv = (const bf16x8*)As[cur];
        const bf16x8* Bsv = (const bf16x8*)Bs[cur];
        bf16x8 af[4], bfr[4];
#pragma unroll
        for (int mi = 0; mi < 4; mi++) af[mi] = Asv[(arow + mi * 16) * 4 + quad];
#pragma unroll
        for (int ni = 0; ni < 4; ni++) bfr[ni] = Bsv[(brow + ni * 16) * 4 + quad];
#pragma unroll
        for (int mi = 0; mi < 4; mi++)
#pragma unroll
            for (int ni = 0; ni < 4; ni++)
                acc[mi][ni] = __builtin_amdgcn_mfma_f32_16x16x32_bf16(
                    af[mi], bfr[ni], acc[mi][ni], 0, 0, 0);
        cur ^= 1;
    }

    int crow = m0 + wm * 64 + (lane >> 4) * 4;
    int ccol = n0 + wn * 64 + (lane & 15);
    const float* biasz = bias ? bias + (z / bzDiv) * bzStride : nullptr;
    float bv[4];
#pragma unroll
    for (int ni = 0; ni < 4; ni++) {
        int col = ccol + ni * 16;
        bv[ni] = (biasz && col < nMax) ? biasz[col] : 0.f;
    }
#pragma unroll
    for (int mi = 0; mi < 4; mi++) {
#pragma unroll
        for (int ni = 0; ni < 4; ni++) {
            int col = ccol + ni * 16;
            if (col >= nMax) continue;
#pragma unroll
            for (int r = 0; r < 4; r++) {
                float v = acc[mi][ni][r] + bv[ni];
                int row = crow + mi * 16 + r;
                long idx = cBase + (long)row * ldc + col;
                if (act == 1) v = fmaxf(v, 0.f);
                else if (act == 2) v = (v > 0.f) ? v : expm1f(v);
                else if (act == 4) {
                    float e = (float)E[(long)z * sCE + (long)row * ldE + col];
                    v = fmaxf(v, 0.f);
                    float g = sigf(e);
                    v = g * v + (1.f - g) * e;
                } else if (act == 5) {
                    float s = (float)E[(long)z * sCE + (long)row * ldE + col];
                    float g = 0.6f * sigf(v);
                    v = (1.f - g) * s + g * v;
                }
                if (Cf) Cf[idx] = v;
                if (Cb) Cb[idx] = (__bf16)v;
            }
        }
    }
}

// ---------------- fused weight transpose-casts (10 weights, one dispatch) -----
struct WCast {
    const float* src[10];
    unsigned dstOff[10];
    int R[10], C[10];
    int start[11];
};

__global__ __launch_bounds__(256) void castW_kernel(WCast wc, __bf16* wb)
{
    __shared__ float t[32][33];
    int bid = blockIdx.x;
    int e = 0;
    while (bid >= wc.start[e + 1]) e++;
    int tt = bid - wc.start[e];
    int cT = wc.C[e] >> 5;
    int ty = tt / cT, tx = tt - ty * cT;
    const float* in = wc.src[e];
    __bf16* out = wb + wc.dstOff[e];
    int R = wc.R[e], C = wc.C[e];
    int r0 = ty * 32, c0 = tx * 32;
    int tid = threadIdx.x;
    int r = tid >> 3, c4 = (tid & 7) * 4;
    float4 v = *(const float4*)(in + (long)(r0 + r) * C + c0 + c4);
    t[r][c4] = v.x; t[r][c4 + 1] = v.y; t[r][c4 + 2] = v.z; t[r][c4 + 3] = v.w;
    __syncthreads();
    int c = tid >> 3, r4 = (tid & 7) * 4;
    bf16x4 o;
    o[0] = (__bf16)t[r4 + 0][c]; o[1] = (__bf16)t[r4 + 1][c];
    o[2] = (__bf16)t[r4 + 2][c]; o[3] = (__bf16)t[r4 + 3][c];
    *(bf16x4*)(out + (long)(c0 + c) * R + r0 + r4) = o;
}

// ---------------- plain casts ----------------
__global__ void cast_bf16_kernel(const float* __restrict__ in, __bf16* __restrict__ out, long n4)
{
    long i = (long)blockIdx.x * blockDim.x + threadIdx.x;
    if (i < n4) {
        float4 v = ((const float4*)in)[i];
        bf16x4 o; o[0] = (__bf16)v.x; o[1] = (__bf16)v.y; o[2] = (__bf16)v.z; o[3] = (__bf16)v.w;
        ((bf16x4*)out)[i] = o;
    }
}

// ---------------- attention softmax + head-mean -> adj_ag (bf16 in/out) -------
__global__ __launch_bounds__(256) void softmax_combine(
    const __bf16* __restrict__ scores, const int* __restrict__ attn_mask,
    __bf16* __restrict__ adj_agb, int b0)
{
    const int S = 512;
    int s = blockIdx.x, bl = blockIdx.y, b = b0 + bl;
    int tid = threadIdx.x;
    const float scale = 0.1020620726159658f;  // 1/sqrt(96)
    int t0 = tid, t1 = tid + 256;
    int cm0 = attn_mask[b * S + t0], cm1 = attn_mask[b * S + t1];
    float vals[8][2], part[8];
#pragma unroll
    for (int h = 0; h < 8; ++h) {
        long rb = ((long)(bl * 8 + h) * S + s) * S;
        float r0 = (float)scores[rb + t0], r1 = (float)scores[rb + t1];
        vals[h][0] = cm0 ? __expf(r0 * scale) : 0.f;
        vals[h][1] = cm1 ? __expf(r1 * scale) : 0.f;
        part[h] = vals[h][0] + vals[h][1];
    }
    __shared__ float red[4][8];
    __shared__ float linv[8];
    int lane = tid & 63, w = tid >> 6;
#pragma unroll
    for (int h = 0; h < 8; ++h) {
        float v = part[h];
        for (int o = 32; o > 0; o >>= 1) v += __shfl_down(v, o);
        if (lane == 0) red[w][h] = v;
    }
    __syncthreads();
    if (tid < 8) {
        float l = red[0][tid] + red[1][tid] + red[2][tid] + red[3][tid];
        linv[tid] = 1.f / fmaxf(l, 1e-30f);
    }
    __syncthreads();
    float rowmask = attn_mask[b * S + s] ? 1.f : 0.f;
    float a0 = 0.f, a1 = 0.f;
#pragma unroll
    for (int h = 0; h < 8; ++h) { a0 += vals[h][0] * linv[h]; a1 += vals[h][1] * linv[h]; }
    a0 *= 0.125f; a1 *= 0.125f;
    if (t0 == s) a0 = 1.f;
    if (t1 == s) a1 = 1.f;
    long ob = ((long)b * S + s) * S;
    adj_agb[ob + t0] = (__bf16)(rowmask * a0);
    adj_agb[ob + t1] = (__bf16)(rowmask * a1);
}

// ---------------- row L2-normalize, bf16 in place ----------------
__global__ __launch_bounds__(128) void rownorm(__bf16* __restrict__ hb, int Dm)
{
    __bf16* p = hb + (long)blockIdx.x * Dm;
    int tid = threadIdx.x;
    float ss = 0.f;
    for (int i = tid; i < Dm; i += 128) { float v = (float)p[i]; ss += v * v; }
    for (int o = 32; o > 0; o >>= 1) ss += __shfl_down(ss, o);
    __shared__ float sb[2];
    __shared__ float scale;
    if ((tid & 63) == 0) sb[tid >> 6] = ss;
    __syncthreads();
    if (tid == 0) scale = 1.f / fmaxf(sqrtf(sb[0] + sb[1]), 1e-12f);
    __syncthreads();
    for (int i = tid; i < Dm; i += 128) p[i] = (__bf16)((float)p[i] * scale);
}

// ---------------- fused symmetric scope loss per (b,s) row (bf16 G) -----------
// G21 is never materialized: G21[b,s,t] == G12[b,t,s] (bitwise-identical MFMA
// sums), read as a strided column gather; adjacent s-blocks share L2 lines.
__global__ __launch_bounds__(256) void loss_kernel(
    const __bf16* __restrict__ G11, const __bf16* __restrict__ G12,
    const __bf16* __restrict__ G22,
    const int* __restrict__ s_mask, const int* __restrict__ a_mask,
    float* __restrict__ lossb)
{
    const int S = 512;
    int s = blockIdx.x, b = blockIdx.y;
    int tid = threadIdx.x;
    if (a_mask[b * S + s] == 0) {
        if (tid == 0) lossb[b * S + s] = 0.f;
        return;
    }
    long base = ((long)b * S + s) * S;
    long cbase = (long)b * S * S + s;  // G12 column s (== G21 row s)
    const float it = 1.f / 0.07f;
    float sms = s_mask[b * S + s] ? 1.f : 0.f;
    float d12 = (float)G12[base + s];          // == G21 diag (same dot product)
    float w1i = sms * d12 * it, w2i = w1i;
    float p[8];
#pragma unroll
    for (int h = 0; h < 8; h++) p[h] = 0.f;
#pragma unroll
    for (int j = 0; j < 2; j++) {
        int t = tid + j * 256;
        bool smt = s_mask[b * S + t] != 0;
        bool off = (t != s);
        float g11 = (float)G11[base + t], g12 = (float)G12[base + t];
        float g21 = (float)G12[cbase + (long)t * S];
        float g22 = (float)G22[base + t];
        float e11 = __expf(g11 * it), e12 = __expf(g12 * it);
        float e21 = __expf(g21 * it), e22 = __expf(g22 * it);
        p[2] += e11; p[3] += e12; p[6] += e22; p[7] += e21;
        if (off) {
            p[0] += smt ? e11 : 1.f;
            p[4] += smt ? e22 : 1.f;
            p[1] += smt ? __expf(g12 * w1i) : 1.f;
            p[5] += smt ? __expf(g21 * w2i) : 1.f;
        }
    }
    __shared__ float red[4][8];
    int lane = tid & 63, w = tid >> 6;
#pragma unroll
    for (int h = 0; h < 8; h++) {
        float v = p[h];
        for (int o = 32; o > 0; o >>= 1) v += __shfl_down(v, o);
        if (lane == 0) red[w][h] = v;
    }
    __syncthreads();
    if (tid == 0) {
        float r[8];
#pragma unroll
        for (int h = 0; h < 8; h++) r[h] = red[0][h] + red[1][h] + red[2][h] + red[3][h];
        float g11ss = (float)G11[base + s], g22ss = (float)G22[base + s];
        float pos1 = __expf(w1i) + r[0] + r[1];
        float alle1 = r[2] - __expf(g11ss * it) + r[3];
        float pos2 = __expf(w2i) + r[4] + r[5];
        float alle2 = r[6] - __expf(g22ss * it) + r[7];
        lossb[b * S + s] = 0.5f * ((__logf(alle1) - __logf(pos1)) +
                                   (__logf(alle2) - __logf(pos2)));
    }
}

__global__ __launch_bounds__(256) void final_reduce(
    const float* __restrict__ lossb, float* __restrict__ out, int n)
{
    int tid = threadIdx.x;
    float s = 0.f;
    for (int i = tid; i < n; i += 256) s += lossb[i];
    for (int o = 32; o > 0; o >>= 1) s += __shfl_down(s, o);
    __shared__ float sb[4];
    if ((tid & 63) == 0) sb[tid >> 6] = s;
    __syncthreads();
    if (tid == 0) out[0] = (sb[0] + sb[1] + sb[2] + sb[3]) / (float)n;
}

// ---------------- host ----------------
static inline void mg(hipStream_t st, const __bf16* A, const __bf16* B,
                      const float* bias, int bzDiv, int bzStride,
                      const __bf16* E, long ldE, long sCE,
                      float* Cf, __bf16* Cb,
                      int M, int Npad, int nMax, int K, int lda, int ldb, int ldc,
                      long sAo, long sAi, long sBo, long sBi, int zInner, long sC, int nz,
                      int act)
{
    dim3 g(M / 128, Npad / 128, nz);
    mfma_gemm<<<g, 256, 0, st>>>(A, B, bias, bzDiv, bzStride, E, ldE, sCE, Cf, Cb,
                                 K, lda, ldb, ldc, nMax,
                                 sAo, sAi, sBo, sBi, zInner, sC, act);
}

extern "C" void kernel_launch(void* const* d_in, const int* in_sizes, int n_in,
                              void* d_out, int out_size, void* d_ws, size_t ws_size,
                              hipStream_t stream)
{
    const int B = 32, S = 512, D = 768, Mm = 384;
    const int MT = B * S;  // 16384
    const float* X    = (const float*)d_in[0];
    const float* adjm = (const float*)d_in[1];
    const int* attn_mask = (const int*)d_in[2];
    const int* s_mask    = (const int*)d_in[3];
    const int* a_mask    = (const int*)d_in[4];
    const float* Wq = (const float*)d_in[5],  *bq = (const float*)d_in[6];
    const float* Wk = (const float*)d_in[7],  *bk = (const float*)d_in[8];
    const float* semW0 = (const float*)d_in[9],  *semb0 = (const float*)d_in[10];
    const float* semW1 = (const float*)d_in[11], *semb1 = (const float*)d_in[12];
    const float* depW0 = (const float*)d_in[13], *depb0 = (const float*)d_in[14];
    const float* depW1 = (const float*)d_in[15], *depb1 = (const float*)d_in[16];
    const float* fc1W = (const float*)d_in[17], *fc1b = (const float*)d_in[18];
    const float* fc2W = (const float*)d_in[19], *fc2b = (const float*)d_in[20];
    const float* fc3W = (const float*)d_in[21], *fc3b = (const float*)d_in[22];
    const float* fc4W = (const float*)d_in[23], *fc4b = (const float*)d_in[24];

    char* ws = (char*)d_ws;
    const size_t MB = 1u << 20;
    const size_t KB = 1u << 10;

    // rotating regions (lifetimes re-audited for the 60MB qkb):
    __bf16* Xb      = (__bf16*)(ws + 0 * MB);     // 24MB  (dead after P64-L0)
    __bf16* adj_agb = (__bf16*)(ws + 24 * MB);    // 16MB \ contiguous, alive ->L1adj
    __bf16* adjmb   = (__bf16*)(ws + 40 * MB);    // 16MB /
    __bf16* qkb     = (__bf16*)(ws + 56 * MB);    // 60MB [MT][1920]: q|k|Hpre
                                                  //   q,k dead after attn;
                                                  //   Hpre cols dead after fc3-L0
    __bf16* scoreB  = (__bf16*)(ws + 116 * MB);   // 64MB (attn only), ends 180
    __bf16* P64     = (__bf16*)(ws + 116 * MB);   // 24MB (layers; scoreB dead)
    __bf16* IsIdb   = (__bf16*)(ws + 140 * MB);   // 12MB Isem only (dep fused)
    __bf16* Isemb   = IsIdb;
    __bf16* Icomb   = (__bf16*)(ws + 152 * MB);   // 12MB
    __bf16* Hb      = (__bf16*)(ws + 164 * MB);   // 12MB
    __bf16* t1b     = (__bf16*)(ws + 176 * MB);   // 2MB (scoreB dead by proj)
    __bf16* hb12    = (__bf16*)(ws + 0 * MB);     // 24MB h1|h2 (Xb dead)
    __bf16* h1b     = hb12;
    __bf16* h2b     = hb12 + (long)MT * Mm;
    __bf16* G11     = (__bf16*)(ws + 24 * MB);    // 16MB (adj_agb dead)
    __bf16* G12     = (__bf16*)(ws + 40 * MB);    // 16MB (adjmb dead)
    __bf16* G22     = (__bf16*)(ws + 56 * MB);    // 16MB (qkb dead)

    // permanent weight region @192MB.  Order: WqT|WkT|fc4WT contiguous so the
    // fused q|k|fc4 dispatch sees one [1920][768] B matrix.
    char* wreg = ws + 192 * MB;
    __bf16* wb     = (__bf16*)wreg;
    __bf16* WqkT   = (__bf16*)(wreg + 0 * KB);       // [1536][768]
    __bf16* fc4WT  = (__bf16*)(wreg + 2304 * KB);    // [384][768]  (contiguous!)
    __bf16* semW0T = (__bf16*)(wreg + 2880 * KB);    // [384][768] \ contiguous
    __bf16* depW0T = (__bf16*)(wreg + 3456 * KB);    //            /
    __bf16* semW1T = (__bf16*)(wreg + 4032 * KB);    // [384][384] \ contiguous
    __bf16* depW1T = (__bf16*)(wreg + 4320 * KB);    //            /
    __bf16* fc3WT  = (__bf16*)(wreg + 4608 * KB);
    __bf16* fc1WT  = (__bf16*)(wreg + 4896 * KB);    // [128 pad][384]
    __bf16* fc2WT  = (__bf16*)(wreg + 4992 * KB);    // [384][32]
    float*  bqkf   = (float*)(wreg + 5016 * KB);     // [1920] bq|bk|fc4b
    float*  sbd0   = (float*)(wreg + 5024 * KB);     // [768] semb0|depb0
    float*  sbd1   = (float*)(wreg + 5028 * KB);     // [768] semb1|depb1
    float*  lossb  = (float*)(wreg + 5036 * KB);     // 64KB

    long nSM = (long)S * Mm, nSS = (long)S * S;
    long nPM = (long)Mm * S;
    const int W = 1920;  // fused q|k|fc4 row width

    // ---- casts ----
    cast_bf16_kernel<<<(MT * D / 4 + 255) / 256, 256, 0, stream>>>(X, Xb, (long)MT * D / 4);
    cast_bf16_kernel<<<((long)B * nSS / 4 + 255) / 256, 256, 0, stream>>>(adjm, adjmb, (long)B * nSS / 4);
    {
        WCast wc;
        const float* srcs[10] = {Wq, Wk, fc4W, semW0, depW0, semW1, depW1, fc3W, fc1W, fc2W};
        unsigned offs[10] = {0u, 589824u, 1179648u, 1474560u, 1769472u,
                             2064384u, 2211840u, 2359296u, 2506752u, 2555904u};
        int Rs[10] = {768, 768, 768, 768, 768, 384, 384, 384, 384, 32};
        int Cs[10] = {768, 768, 384, 384, 384, 384, 384, 384, 32, 384};
        int st = 0;
        for (int i = 0; i < 10; i++) {
            wc.src[i] = srcs[i]; wc.dstOff[i] = offs[i];
            wc.R[i] = Rs[i]; wc.C[i] = Cs[i];
            wc.start[i] = st; st += (Rs[i] / 32) * (Cs[i] / 32);
        }
        wc.start[10] = st;  // 2472
        castW_kernel<<<st, 256, 0, stream>>>(wc, wb);
    }
    hipMemsetAsync(fc1WT + 32 * Mm, 0, (size_t)96 * Mm * 2, stream);
    hipMemcpyAsync(bqkf, bq, D * 4, hipMemcpyDeviceToDevice, stream);
    hipMemcpyAsync(bqkf + D, bk, D * 4, hipMemcpyDeviceToDevice, stream);
    hipMemcpyAsync(bqkf + 2 * D, fc4b, Mm * 4, hipMemcpyDeviceToDevice, stream);
    hipMemcpyAsync(sbd0, semb0, Mm * 4, hipMemcpyDeviceToDevice, stream);
    hipMemcpyAsync(sbd0 + Mm, depb0, Mm * 4, hipMemcpyDeviceToDevice, stream);
    hipMemcpyAsync(sbd1, semb1, Mm * 4, hipMemcpyDeviceToDevice, stream);
    hipMemcpyAsync(sbd1 + Mm, depb1, Mm * 4, hipMemcpyDeviceToDevice, stream);

    // ---- fused q|k|fc4 projection: qkb[MT][1920] = Xb @ [Wq|Wk|fc4W] + b ----
    mg(stream, Xb, WqkT, bqkf, 1, 0, nullptr, 0, 0, nullptr, qkb, MT, W, W, D,
       D, D, W, 0, 0, 0, 0, 1, 0, 1, 0);

    // ---- attention: materialized bf16 scores, 2 chunks of 16 batches ----
    for (int c = 0; c < 2; c++) {
        const __bf16* qc = qkb + (long)c * 16 * S * W;
        mg(stream, qc, qc + 768, nullptr, 1, 0, nullptr, 0, 0, nullptr, scoreB, S, S, S, 96,
           W, W, S, (long)S * W, 96, (long)S * W, 96, 8, nSS, 128, 0);
        softmax_combine<<<dim3(S, 16), 256, 0, stream>>>(scoreB, attn_mask, adj_agb, c * 16);
    }

    // ---- layer 0 ----
    // P64[z<32] = (X_b @ semW0)^T, P64[z>=32] = (X_b @ depW0)^T
    mg(stream, semW0T, Xb, nullptr, 1, 0, nullptr, 0, 0, nullptr, P64, Mm, S, S, D,
       D, D, S, (long)Mm * D, 0, 0, (long)S * D, 32, nPM, 64, 0);
    // sem: Isem = adj_ag @ Psem + semb0
    mg(stream, adj_agb, P64, sbd0, 1, 0, nullptr, 0, 0, nullptr, IsIdb, S, Mm, Mm, S,
       S, S, Mm, 0, nSS, 0, nPM, 32, nSM, 32, 0);
    // dep (fused combine): Icom = (1-0.6 sig(d)) Isem + 0.6 sig(d) d
    mg(stream, adjmb, P64 + 32 * nPM, sbd0 + Mm, 1, 0, IsIdb, Mm, nSM, nullptr, Icomb,
       S, Mm, Mm, S, S, S, Mm, 0, nSS, 0, nPM, 32, nSM, 32, 5);
    // Hb = gate(Hpre(qkb cols 1536+), relu(Icom @ fc3W + fc3b))
    mg(stream, Icomb, fc3WT, fc3b, 1, 0, qkb + 1536, W, 0, nullptr, Hb, MT, Mm, Mm, Mm,
       Mm, Mm, Mm, 0, 0, 0, 0, 1, 0, 1, 4);

    // ---- layer 1 ----
    mg(stream, semW1T, Hb, nullptr, 1, 0, nullptr, 0, 0, nullptr, P64, Mm, S, S, Mm,
       Mm, Mm, S, (long)Mm * Mm, 0, 0, nSM, 32, nPM, 64, 0);
    mg(stream, adj_agb, P64, sbd1, 1, 0, nullptr, 0, 0, nullptr, IsIdb, S, Mm, Mm, S,
       S, S, Mm, 0, nSS, 0, nPM, 32, nSM, 32, 0);
    mg(stream, adjmb, P64 + 32 * nPM, sbd1 + Mm, 1, 0, IsIdb, Mm, nSM, nullptr, Icomb,
       S, Mm, Mm, S, S, S, Mm, 0, nSS, 0, nPM, 32, nSM, 32, 5);
    // Hb = gate(Hb, relu(Icom @ fc3W + fc3b))  (in place; same-thread r-then-w)
    mg(stream, Icomb, fc3WT, fc3b, 1, 0, Hb, Mm, 0, nullptr, Hb, MT, Mm, Mm, Mm,
       Mm, Mm, Mm, 0, 0, 0, 0, 1, 0, 1, 4);

    // ---- projection heads, z=2 (z0: Hb->h1, z1: Isemb->h2) ----
    long sAproj = (long)(Isemb - Hb);  // constant offset between the two A bases
    mg(stream, Hb, fc1WT, fc1b, 1, 0, nullptr, 0, 0, nullptr, t1b, MT, 128, 32, Mm,
       Mm, Mm, 32, 0, sAproj, 0, 0, 2, (long)MT * 32, 2, 2);
    mg(stream, t1b, fc2WT, fc2b, 1, 0, nullptr, 0, 0, nullptr, hb12, MT, Mm, Mm, 32,
       32, 32, Mm, 0, (long)MT * 32, 0, 0, 2, (long)MT * Mm, 2, 0);

    rownorm<<<2 * MT, 128, 0, stream>>>(hb12, Mm);

    // ---- Gram matrices (bf16): G11|G12 (z=64), G22 only (z=32; G21 == G12^T) ----
    mg(stream, h1b, h1b, nullptr, 1, 0, nullptr, 0, 0, nullptr, G11, S, S, S, Mm,
       Mm, Mm, S, 0, nSM, 32 * nSM, nSM, 32, nSS, 64, 0);   // G11 | G12
    mg(stream, h2b, h2b, nullptr, 1, 0, nullptr, 0, 0, nullptr, G22, S, S, S, Mm,
       Mm, Mm, S, 0, nSM, 0, nSM, 32, nSS, 32, 0);          // G22

    // ---- loss ----
    loss_kernel<<<dim3(S, B), 256, 0, stream>>>(G11, G12, G22, s_mask, a_mask, lossb);
    final_reduce<<<1, 256, 0, stream>>>(lossb, (float*)d_out, MT);
}

// Round 9
// 845.328 us; speedup vs baseline: 1.0689x; 1.0040x over previous
//
#include <hip/hip_runtime.h>
#include <math.h>

// DASCO forward, round 18: R17 post-mortem isolated the +55us regression to
// the q|k|fc4 mega-dispatch (163us vs 76+~38 separate; fused N=1920 ran at
// ~296 TF vs 508, and widened qkb's ld slowed the scores GEMMs). The act-5
// gcn-combine epilogue fusion was ~cost-neutral-or-better and is correct.
// This round: exact R15 dispatch graph + workspace (q|k N=1536, separate fc4,
// scoreB ld=1536) keeping ONLY the act-5 fusion (2 dispatches + ~72MB traffic
// saved) and the G21 == G12^T elimination. GEMM core = proven R15 (21%
// MfmaUtil structural ceiling of the m97-like structure at these shapes).
// B=32, S=512, D=768, M=384.

typedef __bf16 bf16x8 __attribute__((ext_vector_type(8)));
typedef __bf16 bf16x4 __attribute__((ext_vector_type(4)));
typedef float f32x4 __attribute__((ext_vector_type(4)));

__device__ __forceinline__ void glds16(const void* g, void* l) {
    __builtin_amdgcn_global_load_lds(
        (const __attribute__((address_space(1))) unsigned*)g,
        (__attribute__((address_space(3))) unsigned*)l, 16, 0, 0);
}

__device__ __forceinline__ float sigf(float x) { return 1.f / (1.f + __expf(-x)); }

// ---------------- bf16 MFMA GEMM, 128x128 tile, dbuf (R15 core) ---------------
// C[z][m][n] = sum_k A[z][m][k]*B[z][n][k] (+bias[(z/bzDiv)*bzStride + n]).
// act: 0 none; 1 relu; 2 elu; 4 gate: g=sig(E), out=g*relu(v)+(1-g)*E;
// 5 gcn-combine: g=0.6*sig(v), out=(1-g)*E+g*v.  E addressed as
// E[z*sCE + row*ldE + col]. n < nMax masked.
__global__ __launch_bounds__(256) void mfma_gemm(
    const __bf16* __restrict__ A, const __bf16* __restrict__ B,
    const float* __restrict__ bias, int bzDiv, int bzStride,
    const __bf16* __restrict__ E, long ldE, long sCE,
    float* __restrict__ Cf, __bf16* __restrict__ Cb,
    int K, int lda, int ldb, int ldc, int nMax,
    long sAo, long sAi, long sBo, long sBi, int zInner, long sC, int act)
{
    __shared__ __bf16 As[2][128 * 32];
    __shared__ __bf16 Bs[2][128 * 32];
    int z = blockIdx.z;
    long aBase = (long)(z / zInner) * sAo + (long)(z % zInner) * sAi;
    long bBase = (long)(z / zInner) * sBo + (long)(z % zInner) * sBi;
    long cBase = (long)z * sC;
    int m0 = blockIdx.x * 128, n0 = blockIdx.y * 128;
    int tid = threadIdx.x;
    int wave = tid >> 6, lane = tid & 63;
    int wm = wave >> 1, wn = wave & 1;

    int e0 = tid, e1 = tid + 256;
    const __bf16* Ag0 = A + aBase + (long)(m0 + (e0 >> 2)) * lda + (e0 & 3) * 8;
    const __bf16* Ag1 = A + aBase + (long)(m0 + (e1 >> 2)) * lda + (e1 & 3) * 8;
    const __bf16* Bg0 = B + bBase + (long)(n0 + (e0 >> 2)) * ldb + (e0 & 3) * 8;
    const __bf16* Bg1 = B + bBase + (long)(n0 + (e1 >> 2)) * ldb + (e1 & 3) * 8;

    f32x4 acc[4][4];
#pragma unroll
    for (int i = 0; i < 4; i++)
#pragma unroll
        for (int j = 0; j < 4; j++) acc[i][j] = (f32x4){0.f, 0.f, 0.f, 0.f};

    int arow = wm * 64 + (lane & 15);
    int brow = wn * 64 + (lane & 15);
    int quad = lane >> 4;

    glds16(Ag0, As[0] + e0 * 8); glds16(Ag1, As[0] + e1 * 8);
    glds16(Bg0, Bs[0] + e0 * 8); glds16(Bg1, Bs[0] + e1 * 8);

    int cur = 0;
    for (int k0 = 0; k0 < K; k0 += 32) {
        __syncthreads();
        if (k0 + 32 < K) {
            int nk = k0 + 32, nb = cur ^ 1;
            glds16(Ag0 + nk, As[nb] + e0 * 8); glds16(Ag1 + nk, As[nb] + e1 * 8);
            glds16(Bg0 + nk, Bs[nb] + e0 * 8); glds16(Bg1 + nk, Bs[nb] + e1 * 8);
        }
        const bf16x8* Asv = (const bf16x8*)As[cur];
        const bf16x8* Bsv = (const bf16x8*)Bs[cur];
        bf16x8 af[4], bfr[4];
#pragma unroll
        for (int mi = 0; mi < 4; mi++) af[mi] = Asv[(arow + mi * 16) * 4 + quad];
#pragma unroll
        for (int ni = 0; ni < 4; ni++) bfr[ni] = Bsv[(brow + ni * 16) * 4 + quad];
#pragma unroll
        for (int mi = 0; mi < 4; mi++)
#pragma unroll
            for (int ni = 0; ni < 4; ni++)
                acc[mi][ni] = __builtin_amdgcn_mfma_f32_16x16x32_bf16(
                    af[mi], bfr[ni], acc[mi][ni], 0, 0, 0);
        cur ^= 1;
    }

    int crow = m0 + wm * 64 + (lane >> 4) * 4;
    int ccol = n0 + wn * 64 + (lane & 15);
    const float* biasz = bias ? bias + (z / bzDiv) * bzStride : nullptr;
    float bv[4];
#pragma unroll
    for (int ni = 0; ni < 4; ni++) {
        int col = ccol + ni * 16;
        bv[ni] = (biasz && col < nMax) ? biasz[col] : 0.f;
    }
#pragma unroll
    for (int mi = 0; mi < 4; mi++) {
#pragma unroll
        for (int ni = 0; ni < 4; ni++) {
            int col = ccol + ni * 16;
            if (col >= nMax) continue;
#pragma unroll
            for (int r = 0; r < 4; r++) {
                float v = acc[mi][ni][r] + bv[ni];
                int row = crow + mi * 16 + r;
                long idx = cBase + (long)row * ldc + col;
                if (act == 1) v = fmaxf(v, 0.f);
                else if (act == 2) v = (v > 0.f) ? v : expm1f(v);
                else if (act == 4) {
                    float e = (float)E[(long)z * sCE + (long)row * ldE + col];
                    v = fmaxf(v, 0.f);
                    float g = sigf(e);
                    v = g * v + (1.f - g) * e;
                } else if (act == 5) {
                    float s = (float)E[(long)z * sCE + (long)row * ldE + col];
                    float g = 0.6f * sigf(v);
                    v = (1.f - g) * s + g * v;
                }
                if (Cf) Cf[idx] = v;
                if (Cb) Cb[idx] = (__bf16)v;
            }
        }
    }
}

// ---------------- fused weight transpose-casts (10 weights, one dispatch) -----
struct WCast {
    const float* src[10];
    unsigned dstOff[10];
    int R[10], C[10];
    int start[11];
};

__global__ __launch_bounds__(256) void castW_kernel(WCast wc, __bf16* wb)
{
    __shared__ float t[32][33];
    int bid = blockIdx.x;
    int e = 0;
    while (bid >= wc.start[e + 1]) e++;
    int tt = bid - wc.start[e];
    int cT = wc.C[e] >> 5;
    int ty = tt / cT, tx = tt - ty * cT;
    const float* in = wc.src[e];
    __bf16* out = wb + wc.dstOff[e];
    int R = wc.R[e], C = wc.C[e];
    int r0 = ty * 32, c0 = tx * 32;
    int tid = threadIdx.x;
    int r = tid >> 3, c4 = (tid & 7) * 4;
    float4 v = *(const float4*)(in + (long)(r0 + r) * C + c0 + c4);
    t[r][c4] = v.x; t[r][c4 + 1] = v.y; t[r][c4 + 2] = v.z; t[r][c4 + 3] = v.w;
    __syncthreads();
    int c = tid >> 3, r4 = (tid & 7) * 4;
    bf16x4 o;
    o[0] = (__bf16)t[r4 + 0][c]; o[1] = (__bf16)t[r4 + 1][c];
    o[2] = (__bf16)t[r4 + 2][c]; o[3] = (__bf16)t[r4 + 3][c];
    *(bf16x4*)(out + (long)(c0 + c) * R + r0 + r4) = o;
}

// ---------------- plain casts ----------------
__global__ void cast_bf16_kernel(const float* __restrict__ in, __bf16* __restrict__ out, long n4)
{
    long i = (long)blockIdx.x * blockDim.x + threadIdx.x;
    if (i < n4) {
        float4 v = ((const float4*)in)[i];
        bf16x4 o; o[0] = (__bf16)v.x; o[1] = (__bf16)v.y; o[2] = (__bf16)v.z; o[3] = (__bf16)v.w;
        ((bf16x4*)out)[i] = o;
    }
}

// ---------------- attention softmax + head-mean -> adj_ag (bf16 in/out) -------
__global__ __launch_bounds__(256) void softmax_combine(
    const __bf16* __restrict__ scores, const int* __restrict__ attn_mask,
    __bf16* __restrict__ adj_agb, int b0)
{
    const int S = 512;
    int s = blockIdx.x, bl = blockIdx.y, b = b0 + bl;
    int tid = threadIdx.x;
    const float scale = 0.1020620726159658f;  // 1/sqrt(96)
    int t0 = tid, t1 = tid + 256;
    int cm0 = attn_mask[b * S + t0], cm1 = attn_mask[b * S + t1];
    float vals[8][2], part[8];
#pragma unroll
    for (int h = 0; h < 8; ++h) {
        long rb = ((long)(bl * 8 + h) * S + s) * S;
        float r0 = (float)scores[rb + t0], r1 = (float)scores[rb + t1];
        vals[h][0] = cm0 ? __expf(r0 * scale) : 0.f;
        vals[h][1] = cm1 ? __expf(r1 * scale) : 0.f;
        part[h] = vals[h][0] + vals[h][1];
    }
    __shared__ float red[4][8];
    __shared__ float linv[8];
    int lane = tid & 63, w = tid >> 6;
#pragma unroll
    for (int h = 0; h < 8; ++h) {
        float v = part[h];
        for (int o = 32; o > 0; o >>= 1) v += __shfl_down(v, o);
        if (lane == 0) red[w][h] = v;
    }
    __syncthreads();
    if (tid < 8) {
        float l = red[0][tid] + red[1][tid] + red[2][tid] + red[3][tid];
        linv[tid] = 1.f / fmaxf(l, 1e-30f);
    }
    __syncthreads();
    float rowmask = attn_mask[b * S + s] ? 1.f : 0.f;
    float a0 = 0.f, a1 = 0.f;
#pragma unroll
    for (int h = 0; h < 8; ++h) { a0 += vals[h][0] * linv[h]; a1 += vals[h][1] * linv[h]; }
    a0 *= 0.125f; a1 *= 0.125f;
    if (t0 == s) a0 = 1.f;
    if (t1 == s) a1 = 1.f;
    long ob = ((long)b * S + s) * S;
    adj_agb[ob + t0] = (__bf16)(rowmask * a0);
    adj_agb[ob + t1] = (__bf16)(rowmask * a1);
}

// ---------------- row L2-normalize, bf16 in place ----------------
__global__ __launch_bounds__(128) void rownorm(__bf16* __restrict__ hb, int Dm)
{
    __bf16* p = hb + (long)blockIdx.x * Dm;
    int tid = threadIdx.x;
    float ss = 0.f;
    for (int i = tid; i < Dm; i += 128) { float v = (float)p[i]; ss += v * v; }
    for (int o = 32; o > 0; o >>= 1) ss += __shfl_down(ss, o);
    __shared__ float sb[2];
    __shared__ float scale;
    if ((tid & 63) == 0) sb[tid >> 6] = ss;
    __syncthreads();
    if (tid == 0) scale = 1.f / fmaxf(sqrtf(sb[0] + sb[1]), 1e-12f);
    __syncthreads();
    for (int i = tid; i < Dm; i += 128) p[i] = (__bf16)((float)p[i] * scale);
}

// ---------------- fused symmetric scope loss per (b,s) row (bf16 G) -----------
// G21 is never materialized: G21[b,s,t] == G12[b,t,s] (bitwise-identical MFMA
// sums), read as a strided column gather; adjacent s-blocks share L2 lines.
__global__ __launch_bounds__(256) void loss_kernel(
    const __bf16* __restrict__ G11, const __bf16* __restrict__ G12,
    const __bf16* __restrict__ G22,
    const int* __restrict__ s_mask, const int* __restrict__ a_mask,
    float* __restrict__ lossb)
{
    const int S = 512;
    int s = blockIdx.x, b = blockIdx.y;
    int tid = threadIdx.x;
    if (a_mask[b * S + s] == 0) {
        if (tid == 0) lossb[b * S + s] = 0.f;
        return;
    }
    long base = ((long)b * S + s) * S;
    long cbase = (long)b * S * S + s;  // G12 column s (== G21 row s)
    const float it = 1.f / 0.07f;
    float sms = s_mask[b * S + s] ? 1.f : 0.f;
    float d12 = (float)G12[base + s];          // == G21 diag (same dot product)
    float w1i = sms * d12 * it, w2i = w1i;
    float p[8];
#pragma unroll
    for (int h = 0; h < 8; h++) p[h] = 0.f;
#pragma unroll
    for (int j = 0; j < 2; j++) {
        int t = tid + j * 256;
        bool smt = s_mask[b * S + t] != 0;
        bool off = (t != s);
        float g11 = (float)G11[base + t], g12 = (float)G12[base + t];
        float g21 = (float)G12[cbase + (long)t * S];
        float g22 = (float)G22[base + t];
        float e11 = __expf(g11 * it), e12 = __expf(g12 * it);
        float e21 = __expf(g21 * it), e22 = __expf(g22 * it);
        p[2] += e11; p[3] += e12; p[6] += e22; p[7] += e21;
        if (off) {
            p[0] += smt ? e11 : 1.f;
            p[4] += smt ? e22 : 1.f;
            p[1] += smt ? __expf(g12 * w1i) : 1.f;
            p[5] += smt ? __expf(g21 * w2i) : 1.f;
        }
    }
    __shared__ float red[4][8];
    int lane = tid & 63, w = tid >> 6;
#pragma unroll
    for (int h = 0; h < 8; h++) {
        float v = p[h];
        for (int o = 32; o > 0; o >>= 1) v += __shfl_down(v, o);
        if (lane == 0) red[w][h] = v;
    }
    __syncthreads();
    if (tid == 0) {
        float r[8];
#pragma unroll
        for (int h = 0; h < 8; h++) r[h] = red[0][h] + red[1][h] + red[2][h] + red[3][h];
        float g11ss = (float)G11[base + s], g22ss = (float)G22[base + s];
        float pos1 = __expf(w1i) + r[0] + r[1];
        float alle1 = r[2] - __expf(g11ss * it) + r[3];
        float pos2 = __expf(w2i) + r[4] + r[5];
        float alle2 = r[6] - __expf(g22ss * it) + r[7];
        lossb[b * S + s] = 0.5f * ((__logf(alle1) - __logf(pos1)) +
                                   (__logf(alle2) - __logf(pos2)));
    }
}

__global__ __launch_bounds__(256) void final_reduce(
    const float* __restrict__ lossb, float* __restrict__ out, int n)
{
    int tid = threadIdx.x;
    float s = 0.f;
    for (int i = tid; i < n; i += 256) s += lossb[i];
    for (int o = 32; o > 0; o >>= 1) s += __shfl_down(s, o);
    __shared__ float sb[4];
    if ((tid & 63) == 0) sb[tid >> 6] = s;
    __syncthreads();
    if (tid == 0) out[0] = (sb[0] + sb[1] + sb[2] + sb[3]) / (float)n;
}

// ---------------- host ----------------
static inline void mg(hipStream_t st, const __bf16* A, const __bf16* B,
                      const float* bias, int bzDiv, int bzStride,
                      const __bf16* E, long ldE, long sCE,
                      float* Cf, __bf16* Cb,
                      int M, int Npad, int nMax, int K, int lda, int ldb, int ldc,
                      long sAo, long sAi, long sBo, long sBi, int zInner, long sC, int nz,
                      int act)
{
    dim3 g(M / 128, Npad / 128, nz);
    mfma_gemm<<<g, 256, 0, st>>>(A, B, bias, bzDiv, bzStride, E, ldE, sCE, Cf, Cb,
                                 K, lda, ldb, ldc, nMax,
                                 sAo, sAi, sBo, sBi, zInner, sC, act);
}

extern "C" void kernel_launch(void* const* d_in, const int* in_sizes, int n_in,
                              void* d_out, int out_size, void* d_ws, size_t ws_size,
                              hipStream_t stream)
{
    const int B = 32, S = 512, D = 768, Mm = 384;
    const int MT = B * S;  // 16384
    const float* X    = (const float*)d_in[0];
    const float* adjm = (const float*)d_in[1];
    const int* attn_mask = (const int*)d_in[2];
    const int* s_mask    = (const int*)d_in[3];
    const int* a_mask    = (const int*)d_in[4];
    const float* Wq = (const float*)d_in[5],  *bq = (const float*)d_in[6];
    const float* Wk = (const float*)d_in[7],  *bk = (const float*)d_in[8];
    const float* semW0 = (const float*)d_in[9],  *semb0 = (const float*)d_in[10];
    const float* semW1 = (const float*)d_in[11], *semb1 = (const float*)d_in[12];
    const float* depW0 = (const float*)d_in[13], *depb0 = (const float*)d_in[14];
    const float* depW1 = (const float*)d_in[15], *depb1 = (const float*)d_in[16];
    const float* fc1W = (const float*)d_in[17], *fc1b = (const float*)d_in[18];
    const float* fc2W = (const float*)d_in[19], *fc2b = (const float*)d_in[20];
    const float* fc3W = (const float*)d_in[21], *fc3b = (const float*)d_in[22];
    const float* fc4W = (const float*)d_in[23], *fc4b = (const float*)d_in[24];

    char* ws = (char*)d_ws;
    const size_t MB = 1u << 20;
    const size_t KB = 1u << 10;

    // rotating regions (R15 layout; IsIdb now holds Isem only)
    __bf16* Xb      = (__bf16*)(ws + 0 * MB);     // 24MB
    __bf16* adj_agb = (__bf16*)(ws + 24 * MB);    // 16MB \ contiguous
    __bf16* adjmb   = (__bf16*)(ws + 40 * MB);    // 16MB /
    __bf16* qkb     = (__bf16*)(ws + 56 * MB);    // 48MB (attn, ld 1536)
    __bf16* scoreB  = (__bf16*)(ws + 104 * MB);   // 64MB chunk (attn), ends 168
    __bf16* P64     = (__bf16*)(ws + 56 * MB);    // 24MB [64][384][512] (layers)
    __bf16* Isemb   = (__bf16*)(ws + 80 * MB);    // 12MB [MT][384] (sem half only)
    __bf16* Icomb   = (__bf16*)(ws + 104 * MB);   // 12MB (scoreB dead)
    __bf16* Hpreb   = (__bf16*)(ws + 116 * MB);   // 12MB (fc4 out, pre-gate)
    __bf16* Hb      = (__bf16*)(ws + 128 * MB);   // 12MB (gated H)
    __bf16* t1b     = (__bf16*)(ws + 0 * MB);     // 2MB, 2 slices (Xb dead)
    __bf16* hb12    = (__bf16*)(ws + 140 * MB);   // 24MB [2][MT][384] h1|h2
    __bf16* h1b     = hb12;
    __bf16* h2b     = hb12 + (long)MT * Mm;
    __bf16* G11     = (__bf16*)(ws + 24 * MB);    // 16MB (adj dead)
    __bf16* G12     = (__bf16*)(ws + 40 * MB);    // 16MB
    __bf16* G22     = (__bf16*)(ws + 72 * MB);    // 16MB (P64/Isem dead by then)

    // permanent weight region @192MB
    char* wreg = ws + 192 * MB;
    __bf16* wb     = (__bf16*)wreg;
    __bf16* WqkT   = (__bf16*)(wreg + 0 * KB);       // [1536][768]
    __bf16* semW0T = (__bf16*)(wreg + 2304 * KB);    // [384][768] \ contiguous
    __bf16* depW0T = (__bf16*)(wreg + 2880 * KB);    //            /
    __bf16* fc4WT  = (__bf16*)(wreg + 3456 * KB);
    __bf16* semW1T = (__bf16*)(wreg + 4032 * KB);    // [384][384] \ contiguous
    __bf16* depW1T = (__bf16*)(wreg + 4320 * KB);    //            /
    __bf16* fc3WT  = (__bf16*)(wreg + 4608 * KB);
    __bf16* fc1WT  = (__bf16*)(wreg + 4896 * KB);    // [128 pad][384]
    __bf16* fc2WT  = (__bf16*)(wreg + 4992 * KB);    // [384][32]
    float*  bqk    = (float*)(wreg + 5016 * KB);     // [1536]
    float*  sbd0   = (float*)(wreg + 5024 * KB);     // [768] semb0|depb0
    float*  sbd1   = (float*)(wreg + 5028 * KB);     // [768] semb1|depb1
    float*  lossb  = (float*)(wreg + 5036 * KB);     // 64KB

    long nSM = (long)S * Mm, nSS = (long)S * S;
    long nPM = (long)Mm * S;

    // ---- casts ----
    cast_bf16_kernel<<<(MT * D / 4 + 255) / 256, 256, 0, stream>>>(X, Xb, (long)MT * D / 4);
    cast_bf16_kernel<<<((long)B * nSS / 4 + 255) / 256, 256, 0, stream>>>(adjm, adjmb, (long)B * nSS / 4);
    {
        WCast wc;
        const float* srcs[10] = {Wq, Wk, semW0, depW0, fc4W, semW1, depW1, fc3W, fc1W, fc2W};
        unsigned offs[10] = {0u, 589824u, 1179648u, 1474560u, 1769472u,
                             2064384u, 2211840u, 2359296u, 2506752u, 2555904u};
        int Rs[10] = {768, 768, 768, 768, 768, 384, 384, 384, 384, 32};
        int Cs[10] = {768, 768, 384, 384, 384, 384, 384, 384, 32, 384};
        int st = 0;
        for (int i = 0; i < 10; i++) {
            wc.src[i] = srcs[i]; wc.dstOff[i] = offs[i];
            wc.R[i] = Rs[i]; wc.C[i] = Cs[i];
            wc.start[i] = st; st += (Rs[i] / 32) * (Cs[i] / 32);
        }
        wc.start[10] = st;  // 2472
        castW_kernel<<<st, 256, 0, stream>>>(wc, wb);
    }
    hipMemsetAsync(fc1WT + 32 * Mm, 0, (size_t)96 * Mm * 2, stream);
    hipMemcpyAsync(bqk, bq, D * 4, hipMemcpyDeviceToDevice, stream);
    hipMemcpyAsync(bqk + D, bk, D * 4, hipMemcpyDeviceToDevice, stream);
    hipMemcpyAsync(sbd0, semb0, Mm * 4, hipMemcpyDeviceToDevice, stream);
    hipMemcpyAsync(sbd0 + Mm, depb0, Mm * 4, hipMemcpyDeviceToDevice, stream);
    hipMemcpyAsync(sbd1, semb1, Mm * 4, hipMemcpyDeviceToDevice, stream);
    hipMemcpyAsync(sbd1 + Mm, depb1, Mm * 4, hipMemcpyDeviceToDevice, stream);

    // ---- fused q|k projection (N=1536, R15) ----
    mg(stream, Xb, WqkT, bqk, 1, 0, nullptr, 0, 0, nullptr, qkb, MT, 1536, 1536, D,
       D, D, 1536, 0, 0, 0, 0, 1, 0, 1, 0);

    // ---- attention: materialized bf16 scores, 2 chunks of 16 batches ----
    for (int c = 0; c < 2; c++) {
        const __bf16* qc = qkb + (long)c * 16 * S * 1536;
        mg(stream, qc, qc + 768, nullptr, 1, 0, nullptr, 0, 0, nullptr, scoreB, S, S, S, 96,
           1536, 1536, S, (long)S * 1536, 96, (long)S * 1536, 96, 8, nSS, 128, 0);
        softmax_combine<<<dim3(S, 16), 256, 0, stream>>>(scoreB, attn_mask, adj_agb, c * 16);
    }

    // ---- layer 0 ----
    // P64[z<32] = (X_b @ semW0)^T, P64[z>=32] = (X_b @ depW0)^T
    mg(stream, semW0T, Xb, nullptr, 1, 0, nullptr, 0, 0, nullptr, P64, Mm, S, S, D,
       D, D, S, (long)Mm * D, 0, 0, (long)S * D, 32, nPM, 64, 0);
    // sem: Isem = adj_ag @ Psem + semb0
    mg(stream, adj_agb, P64, sbd0, 1, 0, nullptr, 0, 0, nullptr, Isemb, S, Mm, Mm, S,
       S, S, Mm, 0, nSS, 0, nPM, 32, nSM, 32, 0);
    // dep (fused gcn-combine): Icom = (1-0.6 sig(d)) Isem + 0.6 sig(d) d
    mg(stream, adjmb, P64 + 32 * nPM, sbd0 + Mm, 1, 0, Isemb, Mm, nSM, nullptr, Icomb,
       S, Mm, Mm, S, S, S, Mm, 0, nSS, 0, nPM, 32, nSM, 32, 5);
    // Hpre = X @ fc4W + fc4b  (bf16)
    mg(stream, Xb, fc4WT, fc4b, 1, 0, nullptr, 0, 0, nullptr, Hpreb, MT, Mm, Mm, D,
       D, D, Mm, 0, 0, 0, 0, 1, 0, 1, 0);
    // Hb = gate(Hpre, relu(Icom @ fc3W + fc3b))
    mg(stream, Icomb, fc3WT, fc3b, 1, 0, Hpreb, Mm, 0, nullptr, Hb, MT, Mm, Mm, Mm,
       Mm, Mm, Mm, 0, 0, 0, 0, 1, 0, 1, 4);

    // ---- layer 1 ----
    mg(stream, semW1T, Hb, nullptr, 1, 0, nullptr, 0, 0, nullptr, P64, Mm, S, S, Mm,
       Mm, Mm, S, (long)Mm * Mm, 0, 0, nSM, 32, nPM, 64, 0);
    mg(stream, adj_agb, P64, sbd1, 1, 0, nullptr, 0, 0, nullptr, Isemb, S, Mm, Mm, S,
       S, S, Mm, 0, nSS, 0, nPM, 32, nSM, 32, 0);
    mg(stream, adjmb, P64 + 32 * nPM, sbd1 + Mm, 1, 0, Isemb, Mm, nSM, nullptr, Icomb,
       S, Mm, Mm, S, S, S, Mm, 0, nSS, 0, nPM, 32, nSM, 32, 5);
    // Hb = gate(Hb, relu(Icom @ fc3W + fc3b))  (in place; same-thread r-then-w)
    mg(stream, Icomb, fc3WT, fc3b, 1, 0, Hb, Mm, 0, nullptr, Hb, MT, Mm, Mm, Mm,
       Mm, Mm, Mm, 0, 0, 0, 0, 1, 0, 1, 4);

    // ---- projection heads, z=2 (z0: Hb->h1, z1: Isemb->h2) ----
    long sAproj = (long)(Isemb - Hb);  // constant offset between the two A bases
    mg(stream, Hb, fc1WT, fc1b, 1, 0, nullptr, 0, 0, nullptr, t1b, MT, 128, 32, Mm,
       Mm, Mm, 32, 0, sAproj, 0, 0, 2, (long)MT * 32, 2, 2);
    mg(stream, t1b, fc2WT, fc2b, 1, 0, nullptr, 0, 0, nullptr, hb12, MT, Mm, Mm, 32,
       32, 32, Mm, 0, (long)MT * 32, 0, 0, 2, (long)MT * Mm, 2, 0);

    rownorm<<<2 * MT, 128, 0, stream>>>(hb12, Mm);

    // ---- Gram matrices (bf16): G11|G12 (z=64), G22 only (z=32; G21 == G12^T) ----
    mg(stream, h1b, h1b, nullptr, 1, 0, nullptr, 0, 0, nullptr, G11, S, S, S, Mm,
       Mm, Mm, S, 0, nSM, 32 * nSM, nSM, 32, nSS, 64, 0);   // G11 | G12
    mg(stream, h2b, h2b, nullptr, 1, 0, nullptr, 0, 0, nullptr, G22, S, S, S, Mm,
       Mm, Mm, S, 0, nSM, 0, nSM, 32, nSS, 32, 0);          // G22

    // ---- loss ----
    loss_kernel<<<dim3(S, B), 256, 0, stream>>>(G11, G12, G22, s_mask, a_mask, lossb);
    final_reduce<<<1, 256, 0, stream>>>(lossb, (float*)d_out, MT);
}

// Round 11
// 792.790 us; speedup vs baseline: 1.1397x; 1.0663x over previous
//
#include <hip/hip_runtime.h>
#include <math.h>

// DASCO forward, round 20: identical resubmit of R19 (GPU acquisition timed
// out — no measurement). R19 = the verified optimum (R15, 793.4us): R0 GEMM
// core (128x128 tile, 4 waves 2x2, acc 4x4 = 140 unified regs, 3 waves/SIMD,
// __syncthreads dbuf) + G21 == G12^T Gram elimination. Nine rounds of
// counter evidence say this structure is at its ceiling (~21% MfmaUtil):
// pipelining null (R10), swizzle null (R10), larger wave tile hits the
// 256-reg unified-RF occupancy cliff (R13/14), B-from-L2 negative (R16),
// N=1920 mega-fusion negative (R17), epilogue fusion + dispatch split
// neutral (R18, after ~7% clock-variance correction). B=32, S=512, D=768,
// M=384.

typedef __bf16 bf16x8 __attribute__((ext_vector_type(8)));
typedef __bf16 bf16x4 __attribute__((ext_vector_type(4)));
typedef float f32x4 __attribute__((ext_vector_type(4)));

__device__ __forceinline__ void glds16(const void* g, void* l) {
    __builtin_amdgcn_global_load_lds(
        (const __attribute__((address_space(1))) unsigned*)g,
        (__attribute__((address_space(3))) unsigned*)l, 16, 0, 0);
}

__device__ __forceinline__ float sigf(float x) { return 1.f / (1.f + __expf(-x)); }

// ---------------- bf16 MFMA GEMM, 128x128 tile, dbuf, m-innermost grid --------
// C[z][m][n] = sum_k A[z][m][k]*B[z][n][k] (+bias[(z/bzDiv)*bzStride + n]),
// act: 0 none; 1 relu; 2 elu; 4 relu+gate (E bf16, H_prev). n < nMax masked.
__global__ __launch_bounds__(256) void mfma_gemm(
    const __bf16* __restrict__ A, const __bf16* __restrict__ B,
    const float* __restrict__ bias, int bzDiv, int bzStride,
    const __bf16* __restrict__ E,
    float* __restrict__ Cf, __bf16* __restrict__ Cb,
    int K, int lda, int ldb, int ldc, int nMax,
    long sAo, long sAi, long sBo, long sBi, int zInner, long sC, int act)
{
    __shared__ __bf16 As[2][128 * 32];
    __shared__ __bf16 Bs[2][128 * 32];
    int z = blockIdx.z;
    long aBase = (long)(z / zInner) * sAo + (long)(z % zInner) * sAi;
    long bBase = (long)(z / zInner) * sBo + (long)(z % zInner) * sBi;
    long cBase = (long)z * sC;
    int m0 = blockIdx.x * 128, n0 = blockIdx.y * 128;
    int tid = threadIdx.x;
    int wave = tid >> 6, lane = tid & 63;
    int wm = wave >> 1, wn = wave & 1;

    int e0 = tid, e1 = tid + 256;
    const __bf16* Ag0 = A + aBase + (long)(m0 + (e0 >> 2)) * lda + (e0 & 3) * 8;
    const __bf16* Ag1 = A + aBase + (long)(m0 + (e1 >> 2)) * lda + (e1 & 3) * 8;
    const __bf16* Bg0 = B + bBase + (long)(n0 + (e0 >> 2)) * ldb + (e0 & 3) * 8;
    const __bf16* Bg1 = B + bBase + (long)(n0 + (e1 >> 2)) * ldb + (e1 & 3) * 8;

    f32x4 acc[4][4];
#pragma unroll
    for (int i = 0; i < 4; i++)
#pragma unroll
        for (int j = 0; j < 4; j++) acc[i][j] = (f32x4){0.f, 0.f, 0.f, 0.f};

    int arow = wm * 64 + (lane & 15);
    int brow = wn * 64 + (lane & 15);
    int quad = lane >> 4;

    glds16(Ag0, As[0] + e0 * 8); glds16(Ag1, As[0] + e1 * 8);
    glds16(Bg0, Bs[0] + e0 * 8); glds16(Bg1, Bs[0] + e1 * 8);

    int cur = 0;
    for (int k0 = 0; k0 < K; k0 += 32) {
        __syncthreads();
        if (k0 + 32 < K) {
            int nk = k0 + 32, nb = cur ^ 1;
            glds16(Ag0 + nk, As[nb] + e0 * 8); glds16(Ag1 + nk, As[nb] + e1 * 8);
            glds16(Bg0 + nk, Bs[nb] + e0 * 8); glds16(Bg1 + nk, Bs[nb] + e1 * 8);
        }
        const bf16x8* Asv = (const bf16x8*)As[cur];
        const bf16x8* Bsv = (const bf16x8*)Bs[cur];
        bf16x8 af[4], bfr[4];
#pragma unroll
        for (int mi = 0; mi < 4; mi++) af[mi] = Asv[(arow + mi * 16) * 4 + quad];
#pragma unroll
        for (int ni = 0; ni < 4; ni++) bfr[ni] = Bsv[(brow + ni * 16) * 4 + quad];
#pragma unroll
        for (int mi = 0; mi < 4; mi++)
#pragma unroll
            for (int ni = 0; ni < 4; ni++)
                acc[mi][ni] = __builtin_amdgcn_mfma_f32_16x16x32_bf16(
                    af[mi], bfr[ni], acc[mi][ni], 0, 0, 0);
        cur ^= 1;
    }

    int crow = m0 + wm * 64 + (lane >> 4) * 4;
    int ccol = n0 + wn * 64 + (lane & 15);
    const float* biasz = bias ? bias + (z / bzDiv) * bzStride : nullptr;
    float bv[4];
#pragma unroll
    for (int ni = 0; ni < 4; ni++) {
        int col = ccol + ni * 16;
        bv[ni] = (biasz && col < nMax) ? biasz[col] : 0.f;
    }
#pragma unroll
    for (int mi = 0; mi < 4; mi++) {
#pragma unroll
        for (int ni = 0; ni < 4; ni++) {
            int col = ccol + ni * 16;
            if (col >= nMax) continue;
#pragma unroll
            for (int r = 0; r < 4; r++) {
                float v = acc[mi][ni][r] + bv[ni];
                long idx = cBase + (long)(crow + mi * 16 + r) * ldc + col;
                if (act == 1) v = fmaxf(v, 0.f);
                else if (act == 2) v = (v > 0.f) ? v : expm1f(v);
                else if (act == 4) {
                    float e = (float)E[idx];
                    v = fmaxf(v, 0.f);
                    float g = sigf(e);
                    v = g * v + (1.f - g) * e;
                }
                if (Cf) Cf[idx] = v;
                if (Cb) Cb[idx] = (__bf16)v;
            }
        }
    }
}

// ---------------- fused weight transpose-casts (10 weights, one dispatch) -----
struct WCast {
    const float* src[10];
    unsigned dstOff[10];
    int R[10], C[10];
    int start[11];
};

__global__ __launch_bounds__(256) void castW_kernel(WCast wc, __bf16* wb)
{
    __shared__ float t[32][33];
    int bid = blockIdx.x;
    int e = 0;
    while (bid >= wc.start[e + 1]) e++;
    int tt = bid - wc.start[e];
    int cT = wc.C[e] >> 5;
    int ty = tt / cT, tx = tt - ty * cT;
    const float* in = wc.src[e];
    __bf16* out = wb + wc.dstOff[e];
    int R = wc.R[e], C = wc.C[e];
    int r0 = ty * 32, c0 = tx * 32;
    int tid = threadIdx.x;
    int r = tid >> 3, c4 = (tid & 7) * 4;
    float4 v = *(const float4*)(in + (long)(r0 + r) * C + c0 + c4);
    t[r][c4] = v.x; t[r][c4 + 1] = v.y; t[r][c4 + 2] = v.z; t[r][c4 + 3] = v.w;
    __syncthreads();
    int c = tid >> 3, r4 = (tid & 7) * 4;
    bf16x4 o;
    o[0] = (__bf16)t[r4 + 0][c]; o[1] = (__bf16)t[r4 + 1][c];
    o[2] = (__bf16)t[r4 + 2][c]; o[3] = (__bf16)t[r4 + 3][c];
    *(bf16x4*)(out + (long)(c0 + c) * R + r0 + r4) = o;
}

// ---------------- plain casts ----------------
__global__ void cast_bf16_kernel(const float* __restrict__ in, __bf16* __restrict__ out, long n4)
{
    long i = (long)blockIdx.x * blockDim.x + threadIdx.x;
    if (i < n4) {
        float4 v = ((const float4*)in)[i];
        bf16x4 o; o[0] = (__bf16)v.x; o[1] = (__bf16)v.y; o[2] = (__bf16)v.z; o[3] = (__bf16)v.w;
        ((bf16x4*)out)[i] = o;
    }
}

// ---------------- attention softmax + head-mean -> adj_ag (bf16 in/out) -------
__global__ __launch_bounds__(256) void softmax_combine(
    const __bf16* __restrict__ scores, const int* __restrict__ attn_mask,
    __bf16* __restrict__ adj_agb, int b0)
{
    const int S = 512;
    int s = blockIdx.x, bl = blockIdx.y, b = b0 + bl;
    int tid = threadIdx.x;
    const float scale = 0.1020620726159658f;  // 1/sqrt(96)
    int t0 = tid, t1 = tid + 256;
    int cm0 = attn_mask[b * S + t0], cm1 = attn_mask[b * S + t1];
    float vals[8][2], part[8];
#pragma unroll
    for (int h = 0; h < 8; ++h) {
        long rb = ((long)(bl * 8 + h) * S + s) * S;
        float r0 = (float)scores[rb + t0], r1 = (float)scores[rb + t1];
        vals[h][0] = cm0 ? __expf(r0 * scale) : 0.f;
        vals[h][1] = cm1 ? __expf(r1 * scale) : 0.f;
        part[h] = vals[h][0] + vals[h][1];
    }
    __shared__ float red[4][8];
    __shared__ float linv[8];
    int lane = tid & 63, w = tid >> 6;
#pragma unroll
    for (int h = 0; h < 8; ++h) {
        float v = part[h];
        for (int o = 32; o > 0; o >>= 1) v += __shfl_down(v, o);
        if (lane == 0) red[w][h] = v;
    }
    __syncthreads();
    if (tid < 8) {
        float l = red[0][tid] + red[1][tid] + red[2][tid] + red[3][tid];
        linv[tid] = 1.f / fmaxf(l, 1e-30f);
    }
    __syncthreads();
    float rowmask = attn_mask[b * S + s] ? 1.f : 0.f;
    float a0 = 0.f, a1 = 0.f;
#pragma unroll
    for (int h = 0; h < 8; ++h) { a0 += vals[h][0] * linv[h]; a1 += vals[h][1] * linv[h]; }
    a0 *= 0.125f; a1 *= 0.125f;
    if (t0 == s) a0 = 1.f;
    if (t1 == s) a1 = 1.f;
    long ob = ((long)b * S + s) * S;
    adj_agb[ob + t0] = (__bf16)(rowmask * a0);
    adj_agb[ob + t1] = (__bf16)(rowmask * a1);
}

// ---------------- gcn combine (bf16 in/out) ----------------
// IsIdb: [2][MT][384] bf16 (sem then dep). Icom = (1-0.6 sig(d)) s + 0.6 sig(d) d
__global__ void gcn_combine2(const __bf16* __restrict__ IsIdb,
                             __bf16* __restrict__ Icomb, long n8)
{
    long i = (long)blockIdx.x * blockDim.x + threadIdx.x;
    if (i >= n8) return;
    bf16x8 sv = ((const bf16x8*)IsIdb)[i];
    bf16x8 dv = ((const bf16x8*)(IsIdb + n8 * 8))[i];
    bf16x8 o;
#pragma unroll
    for (int j = 0; j < 8; j++) {
        float s = (float)sv[j], d = (float)dv[j];
        float g = 0.6f * sigf(d);
        o[j] = (__bf16)((1.f - g) * s + g * d);
    }
    ((bf16x8*)Icomb)[i] = o;
}

// ---------------- row L2-normalize, bf16 in place ----------------
__global__ __launch_bounds__(128) void rownorm(__bf16* __restrict__ hb, int Dm)
{
    __bf16* p = hb + (long)blockIdx.x * Dm;
    int tid = threadIdx.x;
    float ss = 0.f;
    for (int i = tid; i < Dm; i += 128) { float v = (float)p[i]; ss += v * v; }
    for (int o = 32; o > 0; o >>= 1) ss += __shfl_down(ss, o);
    __shared__ float sb[2];
    __shared__ float scale;
    if ((tid & 63) == 0) sb[tid >> 6] = ss;
    __syncthreads();
    if (tid == 0) scale = 1.f / fmaxf(sqrtf(sb[0] + sb[1]), 1e-12f);
    __syncthreads();
    for (int i = tid; i < Dm; i += 128) p[i] = (__bf16)((float)p[i] * scale);
}

// ---------------- fused symmetric scope loss per (b,s) row (bf16 G) -----------
// G21 is never materialized: G21[b,s,t] == G12[b,t,s] (bitwise-identical MFMA
// sums), read as a strided column gather; adjacent s-blocks share L2 lines.
__global__ __launch_bounds__(256) void loss_kernel(
    const __bf16* __restrict__ G11, const __bf16* __restrict__ G12,
    const __bf16* __restrict__ G22,
    const int* __restrict__ s_mask, const int* __restrict__ a_mask,
    float* __restrict__ lossb)
{
    const int S = 512;
    int s = blockIdx.x, b = blockIdx.y;
    int tid = threadIdx.x;
    if (a_mask[b * S + s] == 0) {
        if (tid == 0) lossb[b * S + s] = 0.f;
        return;
    }
    long base = ((long)b * S + s) * S;
    long cbase = (long)b * S * S + s;  // G12 column s (== G21 row s)
    const float it = 1.f / 0.07f;
    float sms = s_mask[b * S + s] ? 1.f : 0.f;
    float d12 = (float)G12[base + s];          // == G21 diag (same dot product)
    float w1i = sms * d12 * it, w2i = w1i;
    float p[8];
#pragma unroll
    for (int h = 0; h < 8; h++) p[h] = 0.f;
#pragma unroll
    for (int j = 0; j < 2; j++) {
        int t = tid + j * 256;
        bool smt = s_mask[b * S + t] != 0;
        bool off = (t != s);
        float g11 = (float)G11[base + t], g12 = (float)G12[base + t];
        float g21 = (float)G12[cbase + (long)t * S];
        float g22 = (float)G22[base + t];
        float e11 = __expf(g11 * it), e12 = __expf(g12 * it);
        float e21 = __expf(g21 * it), e22 = __expf(g22 * it);
        p[2] += e11; p[3] += e12; p[6] += e22; p[7] += e21;
        if (off) {
            p[0] += smt ? e11 : 1.f;
            p[4] += smt ? e22 : 1.f;
            p[1] += smt ? __expf(g12 * w1i) : 1.f;
            p[5] += smt ? __expf(g21 * w2i) : 1.f;
        }
    }
    __shared__ float red[4][8];
    int lane = tid & 63, w = tid >> 6;
#pragma unroll
    for (int h = 0; h < 8; h++) {
        float v = p[h];
        for (int o = 32; o > 0; o >>= 1) v += __shfl_down(v, o);
        if (lane == 0) red[w][h] = v;
    }
    __syncthreads();
    if (tid == 0) {
        float r[8];
#pragma unroll
        for (int h = 0; h < 8; h++) r[h] = red[0][h] + red[1][h] + red[2][h] + red[3][h];
        float g11ss = (float)G11[base + s], g22ss = (float)G22[base + s];
        float pos1 = __expf(w1i) + r[0] + r[1];
        float alle1 = r[2] - __expf(g11ss * it) + r[3];
        float pos2 = __expf(w2i) + r[4] + r[5];
        float alle2 = r[6] - __expf(g22ss * it) + r[7];
        lossb[b * S + s] = 0.5f * ((__logf(alle1) - __logf(pos1)) +
                                   (__logf(alle2) - __logf(pos2)));
    }
}

__global__ __launch_bounds__(256) void final_reduce(
    const float* __restrict__ lossb, float* __restrict__ out, int n)
{
    int tid = threadIdx.x;
    float s = 0.f;
    for (int i = tid; i < n; i += 256) s += lossb[i];
    for (int o = 32; o > 0; o >>= 1) s += __shfl_down(s, o);
    __shared__ float sb[4];
    if ((tid & 63) == 0) sb[tid >> 6] = s;
    __syncthreads();
    if (tid == 0) out[0] = (sb[0] + sb[1] + sb[2] + sb[3]) / (float)n;
}

// ---------------- host ----------------
static inline void mg(hipStream_t st, const __bf16* A, const __bf16* B,
                      const float* bias, int bzDiv, int bzStride,
                      const __bf16* E, float* Cf, __bf16* Cb,
                      int M, int Npad, int nMax, int K, int lda, int ldb, int ldc,
                      long sAo, long sAi, long sBo, long sBi, int zInner, long sC, int nz,
                      int act)
{
    dim3 g(M / 128, Npad / 128, nz);
    mfma_gemm<<<g, 256, 0, st>>>(A, B, bias, bzDiv, bzStride, E, Cf, Cb,
                                 K, lda, ldb, ldc, nMax,
                                 sAo, sAi, sBo, sBi, zInner, sC, act);
}

extern "C" void kernel_launch(void* const* d_in, const int* in_sizes, int n_in,
                              void* d_out, int out_size, void* d_ws, size_t ws_size,
                              hipStream_t stream)
{
    const int B = 32, S = 512, D = 768, Mm = 384;
    const int MT = B * S;  // 16384
    const float* X    = (const float*)d_in[0];
    const float* adjm = (const float*)d_in[1];
    const int* attn_mask = (const int*)d_in[2];
    const int* s_mask    = (const int*)d_in[3];
    const int* a_mask    = (const int*)d_in[4];
    const float* Wq = (const float*)d_in[5],  *bq = (const float*)d_in[6];
    const float* Wk = (const float*)d_in[7],  *bk = (const float*)d_in[8];
    const float* semW0 = (const float*)d_in[9],  *semb0 = (const float*)d_in[10];
    const float* semW1 = (const float*)d_in[11], *semb1 = (const float*)d_in[12];
    const float* depW0 = (const float*)d_in[13], *depb0 = (const float*)d_in[14];
    const float* depW1 = (const float*)d_in[15], *depb1 = (const float*)d_in[16];
    const float* fc1W = (const float*)d_in[17], *fc1b = (const float*)d_in[18];
    const float* fc2W = (const float*)d_in[19], *fc2b = (const float*)d_in[20];
    const float* fc3W = (const float*)d_in[21], *fc3b = (const float*)d_in[22];
    const float* fc4W = (const float*)d_in[23], *fc4b = (const float*)d_in[24];

    char* ws = (char*)d_ws;
    const size_t MB = 1u << 20;
    const size_t KB = 1u << 10;

    // rotating regions
    __bf16* Xb      = (__bf16*)(ws + 0 * MB);     // 24MB
    __bf16* adj_agb = (__bf16*)(ws + 24 * MB);    // 16MB \ contiguous
    __bf16* adjmb   = (__bf16*)(ws + 40 * MB);    // 16MB /
    __bf16* qkb     = (__bf16*)(ws + 56 * MB);    // 48MB (attn)
    __bf16* scoreB  = (__bf16*)(ws + 104 * MB);   // 64MB chunk (attn), ends 168
    __bf16* P64     = (__bf16*)(ws + 56 * MB);    // 24MB [64][384][512] (layers)
    __bf16* IsIdb   = (__bf16*)(ws + 80 * MB);    // 24MB [2][MT][384] bf16
    __bf16* Isemb   = IsIdb;                      // sem half doubles as proj input
    __bf16* Icomb   = (__bf16*)(ws + 104 * MB);   // 12MB (scoreB dead)
    __bf16* Hpreb   = (__bf16*)(ws + 116 * MB);   // 12MB (fc4 out, pre-gate)
    __bf16* Hb      = (__bf16*)(ws + 128 * MB);   // 12MB (gated H)
    __bf16* t1b     = (__bf16*)(ws + 0 * MB);     // 2MB, 2 slices (Xb dead)
    __bf16* hb12    = (__bf16*)(ws + 140 * MB);   // 24MB [2][MT][384] h1|h2
    __bf16* h1b     = hb12;
    __bf16* h2b     = hb12 + (long)MT * Mm;
    __bf16* G11     = (__bf16*)(ws + 24 * MB);    // 16MB (adj dead)
    __bf16* G12     = (__bf16*)(ws + 40 * MB);    // 16MB
    __bf16* G22     = (__bf16*)(ws + 72 * MB);    // 16MB (G21 slot unused)

    // permanent weight region @192MB
    char* wreg = ws + 192 * MB;
    __bf16* wb     = (__bf16*)wreg;
    __bf16* WqkT   = (__bf16*)(wreg + 0 * KB);       // [1536][768]
    __bf16* semW0T = (__bf16*)(wreg + 2304 * KB);    // [384][768] \ contiguous
    __bf16* depW0T = (__bf16*)(wreg + 2880 * KB);    //            /
    __bf16* fc4WT  = (__bf16*)(wreg + 3456 * KB);
    __bf16* semW1T = (__bf16*)(wreg + 4032 * KB);    // [384][384] \ contiguous
    __bf16* depW1T = (__bf16*)(wreg + 4320 * KB);    //            /
    __bf16* fc3WT  = (__bf16*)(wreg + 4608 * KB);
    __bf16* fc1WT  = (__bf16*)(wreg + 4896 * KB);    // [128 pad][384]
    __bf16* fc2WT  = (__bf16*)(wreg + 4992 * KB);    // [384][32]
    float*  bqk    = (float*)(wreg + 5016 * KB);     // [1536]
    float*  sbd0   = (float*)(wreg + 5024 * KB);     // [768] semb0|depb0
    float*  sbd1   = (float*)(wreg + 5028 * KB);     // [768] semb1|depb1
    float*  lossb  = (float*)(wreg + 5036 * KB);     // 64KB

    long nSM = (long)S * Mm, nSS = (long)S * S;
    long nPM = (long)Mm * S;

    // ---- casts ----
    cast_bf16_kernel<<<(MT * D / 4 + 255) / 256, 256, 0, stream>>>(X, Xb, (long)MT * D / 4);
    cast_bf16_kernel<<<((long)B * nSS / 4 + 255) / 256, 256, 0, stream>>>(adjm, adjmb, (long)B * nSS / 4);
    {
        WCast wc;
        const float* srcs[10] = {Wq, Wk, semW0, depW0, fc4W, semW1, depW1, fc3W, fc1W, fc2W};
        unsigned offs[10] = {0u, 589824u, 1179648u, 1474560u, 1769472u,
                             2064384u, 2211840u, 2359296u, 2506752u, 2555904u};
        int Rs[10] = {768, 768, 768, 768, 768, 384, 384, 384, 384, 32};
        int Cs[10] = {768, 768, 384, 384, 384, 384, 384, 384, 32, 384};
        int st = 0;
        for (int i = 0; i < 10; i++) {
            wc.src[i] = srcs[i]; wc.dstOff[i] = offs[i];
            wc.R[i] = Rs[i]; wc.C[i] = Cs[i];
            wc.start[i] = st; st += (Rs[i] / 32) * (Cs[i] / 32);
        }
        wc.start[10] = st;  // 2472
        castW_kernel<<<st, 256, 0, stream>>>(wc, wb);
    }
    hipMemsetAsync(fc1WT + 32 * Mm, 0, (size_t)96 * Mm * 2, stream);
    hipMemcpyAsync(bqk, bq, D * 4, hipMemcpyDeviceToDevice, stream);
    hipMemcpyAsync(bqk + D, bk, D * 4, hipMemcpyDeviceToDevice, stream);
    hipMemcpyAsync(sbd0, semb0, Mm * 4, hipMemcpyDeviceToDevice, stream);
    hipMemcpyAsync(sbd0 + Mm, depb0, Mm * 4, hipMemcpyDeviceToDevice, stream);
    hipMemcpyAsync(sbd1, semb1, Mm * 4, hipMemcpyDeviceToDevice, stream);
    hipMemcpyAsync(sbd1 + Mm, depb1, Mm * 4, hipMemcpyDeviceToDevice, stream);

    // ---- fused q|k projection ----
    mg(stream, Xb, WqkT, bqk, 1, 0, nullptr, nullptr, qkb, MT, 1536, 1536, D,
       D, D, 1536, 0, 0, 0, 0, 1, 0, 1, 0);

    // ---- attention: materialized bf16 scores, 2 chunks of 16 batches ----
    for (int c = 0; c < 2; c++) {
        const __bf16* qc = qkb + (long)c * 16 * S * 1536;
        mg(stream, qc, qc + 768, nullptr, 1, 0, nullptr, nullptr, scoreB, S, S, S, 96,
           1536, 1536, S, (long)S * 1536, 96, (long)S * 1536, 96, 8, nSS, 128, 0);
        softmax_combine<<<dim3(S, 16), 256, 0, stream>>>(scoreB, attn_mask, adj_agb, c * 16);
    }

    long n8 = (long)MT * Mm / 8;
    int cwg = (int)((n8 + 255) / 256);

    // ---- layer 0 ----
    // P64[z<32] = (X_b @ semW0)^T, P64[z>=32] = (X_b @ depW0)^T
    mg(stream, semW0T, Xb, nullptr, 1, 0, nullptr, nullptr, P64, Mm, S, S, D,
       D, D, S, (long)Mm * D, 0, 0, (long)S * D, 32, nPM, 64, 0);
    // merged adjacency: z<32 adj_ag@Psem+semb0 -> Isem; z>=32 adjm@Pdep+depb0 -> Idep (bf16)
    mg(stream, adj_agb, P64, sbd0, 32, Mm, nullptr, nullptr, IsIdb, S, Mm, Mm, S,
       S, S, Mm, 0, nSS, 0, nPM, 64, nSM, 64, 0);
    gcn_combine2<<<cwg, 256, 0, stream>>>(IsIdb, Icomb, n8);
    // Hpre = X @ fc4W + fc4b  (bf16)
    mg(stream, Xb, fc4WT, fc4b, 1, 0, nullptr, nullptr, Hpreb, MT, Mm, Mm, D,
       D, D, Mm, 0, 0, 0, 0, 1, 0, 1, 0);
    // Hb = gate(Hpre, relu(Icom @ fc3W + fc3b))
    mg(stream, Icomb, fc3WT, fc3b, 1, 0, Hpreb, nullptr, Hb, MT, Mm, Mm, Mm,
       Mm, Mm, Mm, 0, 0, 0, 0, 1, 0, 1, 4);

    // ---- layer 1 ----
    mg(stream, semW1T, Hb, nullptr, 1, 0, nullptr, nullptr, P64, Mm, S, S, Mm,
       Mm, Mm, S, (long)Mm * Mm, 0, 0, nSM, 32, nPM, 64, 0);
    mg(stream, adj_agb, P64, sbd1, 32, Mm, nullptr, nullptr, IsIdb, S, Mm, Mm, S,
       S, S, Mm, 0, nSS, 0, nPM, 64, nSM, 64, 0);
    gcn_combine2<<<cwg, 256, 0, stream>>>(IsIdb, Icomb, n8);
    // Hb = gate(Hb, relu(Icom @ fc3W + fc3b))  (in place; per-thread read-then-write)
    mg(stream, Icomb, fc3WT, fc3b, 1, 0, Hb, nullptr, Hb, MT, Mm, Mm, Mm,
       Mm, Mm, Mm, 0, 0, 0, 0, 1, 0, 1, 4);

    // ---- projection heads, z=2 (z0: Hb->h1, z1: Isemb->h2) ----
    long sAproj = (long)(Isemb - Hb);  // constant offset between the two A bases
    mg(stream, Hb, fc1WT, fc1b, 1, 0, nullptr, nullptr, t1b, MT, 128, 32, Mm,
       Mm, Mm, 32, 0, sAproj, 0, 0, 2, (long)MT * 32, 2, 2);
    mg(stream, t1b, fc2WT, fc2b, 1, 0, nullptr, nullptr, hb12, MT, Mm, Mm, 32,
       32, 32, Mm, 0, (long)MT * 32, 0, 0, 2, (long)MT * Mm, 2, 0);

    rownorm<<<2 * MT, 128, 0, stream>>>(hb12, Mm);

    // ---- Gram matrices (bf16): G11|G12 (z=64), G22 only (z=32; G21 == G12^T) ----
    mg(stream, h1b, h1b, nullptr, 1, 0, nullptr, nullptr, G11, S, S, S, Mm,
       Mm, Mm, S, 0, nSM, 32 * nSM, nSM, 32, nSS, 64, 0);   // G11 | G12
    mg(stream, h2b, h2b, nullptr, 1, 0, nullptr, nullptr, G22, S, S, S, Mm,
       Mm, Mm, S, 0, nSM, 0, nSM, 32, nSS, 32, 0);          // G22

    // ---- loss ----
    loss_kernel<<<dim3(S, B), 256, 0, stream>>>(G11, G12, G22, s_mask, a_mask, lossb);
    final_reduce<<<1, 256, 0, stream>>>(lossb, (float*)d_out, MT);
}